// Round 14
// baseline (444.552 us; speedup 1.0000x reference)
//
#include <hip/hip_runtime.h>
#include <hip/hip_bf16.h>

#define B_    2
#define L_    2048
#define DM_   1024
#define DI_   2048
#define DS_   16
#define DTR_  64
#define KC_   8

typedef __bf16 v8bf __attribute__((ext_vector_type(8)));
typedef float  v4f  __attribute__((ext_vector_type(4)));
typedef unsigned short us8 __attribute__((ext_vector_type(8)));

// HW packed fp32->bf16 (RNE): lo -> bits[15:0], hi -> bits[31:16].
__device__ __forceinline__ unsigned cvt_pk_bf16(float lo, float hi) {
  unsigned r;
  asm("v_cvt_pk_bf16_f32 %0, %1, %2" : "=v"(r) : "v"(lo), "v"(hi));
  return r;
}

// DPP row_shr reduction step; after shifts 1,2,4,8 the row sum lands in lane 15.
template<int CTRL>
__device__ __forceinline__ float dpp_shr_add(float x) {
  int xi = __builtin_bit_cast(int, x);
  int yi = __builtin_amdgcn_update_dpp(xi, xi, CTRL, 0xF, 0xF, true);
  return x + __builtin_bit_cast(float, yi);
}

// ---------------------------------------------------------------------------
// bf16 MFMA GEMM, 128x128 tile, BK=32, 4 waves (2x2), 16x16x32 MFMA.
// (round-12 exact: cvt_pk staging)
// ---------------------------------------------------------------------------
template<int BCOL, int CT>
__global__ __launch_bounds__(256) void gemm_mfma(
    const float* __restrict__ A, const float* __restrict__ B,
    float* __restrict__ C,
    int M, int N, int K, int lda, int ldb, int ldc,
    long long sA, long long sB_, long long sC)
{
  __shared__ unsigned short lA[128 * 32];
  __shared__ unsigned short lB[128 * 32];

  const int tid  = threadIdx.x;
  const int bz   = blockIdx.z;
  A += sA  * bz;
  B += sB_ * bz;
  C += sC  * bz;

  const int m0 = blockIdx.y * 128;
  const int n0 = blockIdx.x * 128;
  const int wave = tid >> 6, lane = tid & 63;
  const int wr = wave >> 1, wc = wave & 1;
  const int lrow = lane & 15, lk = lane >> 4;

  v4f acc[4][4];
  #pragma unroll
  for (int i = 0; i < 4; ++i)
    #pragma unroll
    for (int j = 0; j < 4; ++j) acc[i][j] = (v4f)0.f;

  const int sr  = tid >> 1, skh = (tid & 1) * 16;
  const int cn4 = (tid & 31) * 4, ck4 = (tid >> 5) * 4;

  for (int k0 = 0; k0 < K; k0 += 32) {
    __syncthreads();
    {
      const float* src = A + (long long)(m0 + sr) * lda + k0 + skh;
      unsigned t32[8];
      #pragma unroll
      for (int q = 0; q < 4; ++q) {
        float4 v = *(const float4*)(src + q * 4);
        t32[2*q]   = cvt_pk_bf16(v.x, v.y);
        t32[2*q+1] = cvt_pk_bf16(v.z, v.w);
      }
      int b0 = sr * 64 + skh * 2;
      int sw = (sr & 7) << 4;
      *(uint4*)((char*)lA + ((b0)      ^ sw)) = *(uint4*)&t32[0];
      *(uint4*)((char*)lA + ((b0 + 16) ^ sw)) = *(uint4*)&t32[4];
    }
    if (BCOL == 0) {
      const float* src = B + (long long)(n0 + sr) * ldb + k0 + skh;
      unsigned t32[8];
      #pragma unroll
      for (int q = 0; q < 4; ++q) {
        float4 v = *(const float4*)(src + q * 4);
        t32[2*q]   = cvt_pk_bf16(v.x, v.y);
        t32[2*q+1] = cvt_pk_bf16(v.z, v.w);
      }
      int b0 = sr * 64 + skh * 2;
      int sw = (sr & 7) << 4;
      *(uint4*)((char*)lB + ((b0)      ^ sw)) = *(uint4*)&t32[0];
      *(uint4*)((char*)lB + ((b0 + 16) ^ sw)) = *(uint4*)&t32[4];
    } else {
      float va[4][4];
      #pragma unroll
      for (int kk = 0; kk < 4; ++kk) {
        float4 v = *(const float4*)(B + (long long)(k0 + ck4 + kk) * ldb + n0 + cn4);
        va[kk][0] = v.x; va[kk][1] = v.y; va[kk][2] = v.z; va[kk][3] = v.w;
      }
      #pragma unroll
      for (int nn = 0; nn < 4; ++nn) {
        unsigned w01 = cvt_pk_bf16(va[0][nn], va[1][nn]);
        unsigned w23 = cvt_pk_bf16(va[2][nn], va[3][nn]);
        int row = cn4 + nn;
        int b0  = row * 64 + ck4 * 2;
        unsigned* dst = (unsigned*)((char*)lB + (b0 ^ ((row & 7) << 4)));
        dst[0] = w01;
        dst[1] = w23;
      }
    }
    __syncthreads();

    v8bf af[4], bf[4];
    #pragma unroll
    for (int i = 0; i < 4; ++i) {
      int r  = wr * 64 + i * 16 + lrow;
      int b0 = (r * 64 + lk * 16) ^ ((r & 7) << 4);
      af[i] = __builtin_bit_cast(v8bf, *(const us8*)((const char*)lA + b0));
    }
    #pragma unroll
    for (int j = 0; j < 4; ++j) {
      int r  = wc * 64 + j * 16 + lrow;
      int b0 = (r * 64 + lk * 16) ^ ((r & 7) << 4);
      bf[j] = __builtin_bit_cast(v8bf, *(const us8*)((const char*)lB + b0));
    }
    #pragma unroll
    for (int i = 0; i < 4; ++i)
      #pragma unroll
      for (int j = 0; j < 4; ++j)
        acc[i][j] = __builtin_amdgcn_mfma_f32_16x16x32_bf16(af[i], bf[j], acc[i][j], 0, 0, 0);
  }

  #pragma unroll
  for (int i = 0; i < 4; ++i) {
    #pragma unroll
    for (int j = 0; j < 4; ++j) {
      int gm = m0 + wr * 64 + i * 16 + lk * 4;
      int gn = n0 + wc * 64 + j * 16 + lrow;
      if (CT == 0) {
        #pragma unroll
        for (int r = 0; r < 4; ++r)
          C[(long long)(gm + r) * ldc + gn] = acc[i][j][r];
      } else {
        *(v4f*)&C[(long long)gn * ldc + gm] = acc[i][j];
      }
    }
  }
}

// ---------------------------------------------------------------------------
// Generic 64x64x16 fp32 tiled GEMM. ACT 1: softplus(acc + bias[m]) epilogue.
// ---------------------------------------------------------------------------
template<int AMODE, int BMODE, int ACT>
__global__ __launch_bounds__(256) void gemm64(
    const float* __restrict__ A, const float* __restrict__ B,
    float* __restrict__ C, const float* __restrict__ bias,
    int M, int N, int K, int lda, int ldb, int ldc,
    long long sA, long long sB_, long long sC)
{
  constexpr int BM = 64, BN = 64, BK = 16;
  __shared__ float As[BK][BM + 4];
  __shared__ float Bs[BK][BN + 4];

  const int tid = threadIdx.x;
  const int bz  = blockIdx.z;
  A += sA  * bz;
  B += sB_ * bz;
  C += sC  * bz;

  const int m0 = blockIdx.y * BM;
  const int n0 = blockIdx.x * BN;
  const int tx = tid & 15;
  const int ty = tid >> 4;

  float acc[4][4] = {};

  for (int k0 = 0; k0 < K; k0 += BK) {
    #pragma unroll
    for (int i = 0; i < 4; ++i) {
      int idx = tid + i * 256;
      int m, k;
      if (AMODE == 0) { k = idx & (BK - 1); m = idx >> 4; }
      else            { m = idx & (BM - 1); k = idx >> 6; }
      int gm = m0 + m;
      float v = 0.f;
      if (gm < M)
        v = (AMODE == 0) ? A[(long long)gm * lda + (k0 + k)]
                         : A[(long long)(k0 + k) * lda + gm];
      As[k][m] = v;
    }
    #pragma unroll
    for (int i = 0; i < 4; ++i) {
      int idx = tid + i * 256;
      int n, k;
      if (BMODE == 0) { k = idx & (BK - 1); n = idx >> 4; }
      else            { n = idx & (BN - 1); k = idx >> 6; }
      int gn = n0 + n;
      float v = (BMODE == 0) ? B[(long long)gn * ldb + (k0 + k)]
                             : B[(long long)(k0 + k) * ldb + gn];
      Bs[k][n] = v;
    }
    __syncthreads();

    #pragma unroll
    for (int k = 0; k < BK; ++k) {
      float4 av = *(const float4*)&As[k][ty * 4];
      float4 bv = *(const float4*)&Bs[k][tx * 4];
      float a_[4] = {av.x, av.y, av.z, av.w};
      float b_[4] = {bv.x, bv.y, bv.z, bv.w};
      #pragma unroll
      for (int i = 0; i < 4; ++i)
        #pragma unroll
        for (int j = 0; j < 4; ++j)
          acc[i][j] = fmaf(a_[i], b_[j], acc[i][j]);
    }
    __syncthreads();
  }

  #pragma unroll
  for (int i = 0; i < 4; ++i) {
    int gm = m0 + ty * 4 + i;
    if (gm < M) {
      float bv = (ACT == 1) ? bias[gm] : 0.f;
      #pragma unroll
      for (int j = 0; j < 4; ++j) {
        float v = acc[i][j];
        if (ACT == 1) {
          v += bv;
          v = (v > 20.f) ? v : __logf(1.f + __expf(v));
        }
        C[(long long)gm * ldc + n0 + tx * 4 + j] = v;
      }
    }
  }
}

// ---------------------------------------------------------------------------
// Split-K partials GEMM for K3 (round-9 exact). No atomics.
// ---------------------------------------------------------------------------
__global__ __launch_bounds__(256) void gemm64_p(
    const float* __restrict__ A, const float* __restrict__ B,
    float* __restrict__ part,
    int M, int N, int K, int lda, int ldb,
    long long sB_)
{
  constexpr int BM = 64, BN = 64, BK = 16;
  __shared__ float As[BK][BM + 4];
  __shared__ float Bs[BK][BN + 4];

  const int tid = threadIdx.x;
  const int bz  = blockIdx.z;
  B += sB_ * bz;

  const int m0  = (blockIdx.y & 1) * BM;
  const int kc  = blockIdx.y >> 1;
  const int n0  = blockIdx.x * BN;
  const int kend = (kc + 1) * (K / KC_);
  const int tx = tid & 15;
  const int ty = tid >> 4;

  float* Cp = part + ((size_t)(kc * B_ + bz) * 96) * (size_t)L_;

  float acc[4][4] = {};

  for (int k0 = kc * (K / KC_); k0 < kend; k0 += BK) {
    #pragma unroll
    for (int i = 0; i < 4; ++i) {
      int idx = tid + i * 256;
      int k = idx & (BK - 1), m = idx >> 4;
      int gm = m0 + m;
      As[k][m] = (gm < M) ? A[(long long)gm * lda + (k0 + k)] : 0.f;
    }
    #pragma unroll
    for (int i = 0; i < 4; ++i) {
      int idx = tid + i * 256;
      int n = idx & (BN - 1), k = idx >> 6;
      Bs[k][n] = B[(long long)(k0 + k) * ldb + (n0 + n)];
    }
    __syncthreads();

    #pragma unroll
    for (int k = 0; k < BK; ++k) {
      float4 av = *(const float4*)&As[k][ty * 4];
      float4 bv = *(const float4*)&Bs[k][tx * 4];
      float a_[4] = {av.x, av.y, av.z, av.w};
      float b_[4] = {bv.x, bv.y, bv.z, bv.w};
      #pragma unroll
      for (int i = 0; i < 4; ++i)
        #pragma unroll
        for (int j = 0; j < 4; ++j)
          acc[i][j] = fmaf(a_[i], b_[j], acc[i][j]);
    }
    __syncthreads();
  }

  #pragma unroll
  for (int i = 0; i < 4; ++i) {
    int gm = m0 + ty * 4 + i;
    if (gm < M)
      *(float4*)&Cp[(size_t)gm * L_ + n0 + tx * 4] = *(float4*)&acc[i][0];
  }
}

// reduce KC_ partial slabs -> x_dbl (all 96 rows). One float4 per thread.
__global__ __launch_bounds__(256) void k3_reduce(
    const float* __restrict__ part, float* __restrict__ xdbl)
{
  int i   = blockIdx.x * 256 + threadIdx.x;     // [0, B*96*L/4)
  int l4  = (i & (L_ / 4 - 1)) << 2;
  int row = i >> 9;                              // b*96 + r
  float4 a = make_float4(0.f, 0.f, 0.f, 0.f);
  #pragma unroll
  for (int kc = 0; kc < KC_; ++kc) {
    float4 v = *(const float4*)&part[((size_t)(kc * B_ * 96 + row)) * L_ + l4];
    a.x += v.x; a.y += v.y; a.z += v.z; a.w += v.w;
  }
  *(float4*)&xdbl[(size_t)row * L_ + l4] = a;
}

// ---------------------------------------------------------------------------
// B/C transpose: xdbl rows 64..96 ([k][l]) -> BCt[b][l][n][2] = (B_n(l), C_n(l)).
// BCt occupies xdbl's rows-0..64 region (dead after K4) — run AFTER K4.
// Reads [524288,786432)+[1310720,1572864) B; writes [0,524288) B. Disjoint.
// ---------------------------------------------------------------------------
__global__ __launch_bounds__(256) void bc_transpose(
    const float* __restrict__ xdbl, float* __restrict__ BCt)
{
  const int b  = blockIdx.y;
  const int l0 = blockIdx.x * 64;
  const int t  = threadIdx.x;
  __shared__ float st[32][65];

  // stage: 32 rows (B then C) x 64 cols, 8 floats/thread, coalesced per row
  {
    int r = t >> 3, c8 = (t & 7) * 8;
    const float* src = xdbl + ((size_t)(b * 96 + DTR_ + r)) * L_ + l0 + c8;
    float4 a = *(const float4*)src;
    float4 c = *(const float4*)(src + 4);
    st[r][c8+0] = a.x; st[r][c8+1] = a.y; st[r][c8+2] = a.z; st[r][c8+3] = a.w;
    st[r][c8+4] = c.x; st[r][c8+5] = c.y; st[r][c8+6] = c.z; st[r][c8+7] = c.w;
  }
  __syncthreads();

  // write: thread -> (l, quarter of n-range), interleaved (B,C) pairs
  {
    int lc = t >> 2, q4 = (t & 3) * 4;
    int l  = l0 + lc;
    float o[8];
    #pragma unroll
    for (int i = 0; i < 4; ++i) {
      o[2*i]   = st[q4 + i][lc];        // B_n
      o[2*i+1] = st[16 + q4 + i][lc];   // C_n
    }
    float* dst = BCt + ((size_t)b * L_ + l) * 32 + q4 * 2;
    *(float4*)dst       = *(const float4*)&o[0];
    *(float4*)(dst + 4) = *(const float4*)&o[4];
  }
}

// ---------------------------------------------------------------------------
// Depthwise causal conv (k=4) + bias + SiLU (round-1 exact).
// ---------------------------------------------------------------------------
__global__ __launch_bounds__(256) void conv_silu_kernel(
    const float* __restrict__ xz, const float* __restrict__ cw,
    const float* __restrict__ cb, float* __restrict__ xc)
{
  int idx = blockIdx.x * 256 + threadIdx.x;
  int l4  = (idx & (L_ / 4 - 1)) << 2;
  int row = idx >> 9;
  int d   = row & (DI_ - 1);
  int b   = row >> 11;

  const float* in = xz + ((size_t)b * 2 * DI_ + d) * L_;
  float w0 = cw[d * 4 + 0], w1 = cw[d * 4 + 1];
  float w2 = cw[d * 4 + 2], w3 = cw[d * 4 + 3];
  float bias = cb[d];

  float o[4];
  #pragma unroll
  for (int j = 0; j < 4; ++j) {
    int l = l4 + j;
    float acc = bias + in[l] * w3;
    if (l >= 1) acc += in[l - 1] * w2;
    if (l >= 2) acc += in[l - 2] * w1;
    if (l >= 3) acc += in[l - 3] * w0;
    float sig = 1.f / (1.f + __expf(-acc));
    o[j] = acc * sig;
  }
  *(float4*)&xc[(size_t)row * L_ + l4] = *(float4*)o;
}

// ---------------------------------------------------------------------------
// Gate kernel: y = y_pre * z * sigmoid(z) in place (round-13 exact).
// ---------------------------------------------------------------------------
__global__ __launch_bounds__(256) void gate_silu_kernel(float* __restrict__ xz)
{
  int idx = blockIdx.x * 256 + threadIdx.x;       // [0, B*DI*L/4)
  int l4  = (idx & (L_ / 4 - 1)) << 2;
  int row = idx >> 9;                              // b*DI + d
  int d   = row & (DI_ - 1);
  int b   = row >> 11;

  float*       y = xz + ((size_t)b * 2 * DI_ + d) * L_;
  const float* z = xz + ((size_t)b * 2 * DI_ + DI_ + d) * L_;

  float4 yv = *(const float4*)&y[l4];
  float4 zv = *(const float4*)&z[l4];
  float o[4] = {yv.x, yv.y, yv.z, yv.w};
  float zz[4] = {zv.x, zv.y, zv.z, zv.w};
  #pragma unroll
  for (int j = 0; j < 4; ++j) {
    float sig = 1.f / (1.f + __expf(-zz[j]));
    o[j] = o[j] * zz[j] * sig;
  }
  *(float4*)&y[l4] = *(const float4*)o;
}

// ---------------------------------------------------------------------------
// Selective scan v7: barrier-free, LDS-free. B/C via pre-transposed BCt —
// lane n loads one coalesced float2 (B_n, C_n) per step (identical across the
// wave's 4 groups -> merged). dv/x group-uniform direct loads. Depth-1
// register pipeline on everything. DPP reduce -> lane 15 writes y_pre.
// ---------------------------------------------------------------------------
__global__ __launch_bounds__(256) void scan_kernel(
    float* __restrict__ xz, const float* __restrict__ xconv,
    const float* __restrict__ BCt, const float* __restrict__ A_log,
    const float* __restrict__ Dw)
{
  const int tid = threadIdx.x;
  const int g   = tid >> 4;
  const int n   = tid & 15;
  const int gid = blockIdx.x * 16 + g;
  const int b   = gid >> 11;
  const int d   = gid & (DI_ - 1);

  const float An = -expf(A_log[d * DS_ + n]);
  const float Dd = Dw[d];

  const float* drow = xz    + ((size_t)b * 2 * DI_ + d) * L_;
  const float* xrow = xconv + ((size_t)b * DI_ + d) * L_;
  float*       yrow = xz    + ((size_t)b * 2 * DI_ + d) * L_;
  const float* bc   = BCt + ((size_t)b * L_ * 16 + n) * 2;   // + l*32 per step

  // prefetch batch 0
  float4 nD0 = *(const float4*)&drow[0], nD1 = *(const float4*)&drow[4];
  float4 nX0 = *(const float4*)&xrow[0], nX1 = *(const float4*)&xrow[4];
  float2 nBC[8];
  #pragma unroll
  for (int j = 0; j < 8; ++j) nBC[j] = *(const float2*)&bc[j * 32];

  float h = 0.f;
  for (int l8 = 0; l8 < L_; l8 += 8) {
    float dv[8], xv[8];
    float2 bcv[8];
    *(float4*)&dv[0] = nD0; *(float4*)&dv[4] = nD1;
    *(float4*)&xv[0] = nX0; *(float4*)&xv[4] = nX1;
    #pragma unroll
    for (int j = 0; j < 8; ++j) bcv[j] = nBC[j];

    // issue next batch's loads; land during this batch's compute
    if (l8 + 8 < L_) {
      nD0 = *(const float4*)&drow[l8 + 8]; nD1 = *(const float4*)&drow[l8 + 12];
      nX0 = *(const float4*)&xrow[l8 + 8]; nX1 = *(const float4*)&xrow[l8 + 12];
      #pragma unroll
      for (int j = 0; j < 8; ++j) nBC[j] = *(const float2*)&bc[(l8 + 8 + j) * 32];
    }

    // h-independent work (ILP across 8 steps)
    float dA[8], dBu[8];
    #pragma unroll
    for (int j = 0; j < 8; ++j) {
      dA[j]  = __expf(dv[j] * An);
      dBu[j] = dv[j] * bcv[j].x * xv[j];
    }
    // serial chain: 8 dependent fmas
    float p[8];
    #pragma unroll
    for (int j = 0; j < 8; ++j) {
      h = fmaf(dA[j], h, dBu[j]);
      p[j] = h * bcv[j].y;
    }
    // 8 interleaved DPP reduction trees; sum lands in lane n=15
    #pragma unroll
    for (int j = 0; j < 8; ++j) p[j] = dpp_shr_add<0x111>(p[j]);
    #pragma unroll
    for (int j = 0; j < 8; ++j) p[j] = dpp_shr_add<0x112>(p[j]);
    #pragma unroll
    for (int j = 0; j < 8; ++j) p[j] = dpp_shr_add<0x114>(p[j]);
    #pragma unroll
    for (int j = 0; j < 8; ++j) p[j] = dpp_shr_add<0x118>(p[j]);

    if (n == 15) {
      float o[8];
      #pragma unroll
      for (int j = 0; j < 8; ++j)
        o[j] = p[j] + xv[j] * Dd;            // y_pre; gating applied later
      *(float4*)&yrow[l8]     = *(const float4*)&o[0];
      *(float4*)&yrow[l8 + 4] = *(const float4*)&o[4];
    }
  }
}

// ---------------------------------------------------------------------------
extern "C" void kernel_launch(void* const* d_in, const int* in_sizes, int n_in,
                              void* d_out, int out_size, void* d_ws, size_t ws_size,
                              hipStream_t stream)
{
  const float* hs   = (const float*)d_in[0];
  const float* w1   = (const float*)d_in[1];
  const float* cw   = (const float*)d_in[2];
  const float* cb   = (const float*)d_in[3];
  const float* xpw  = (const float*)d_in[4];
  const float* dtw  = (const float*)d_in[5];
  const float* dtbp = (const float*)d_in[6];
  const float* Alog = (const float*)d_in[7];
  const float* Dw   = (const float*)d_in[8];
  const float* wo   = (const float*)d_in[9];
  float* out = (float*)d_out;

  char* ws = (char*)d_ws;
  float* xz    = (float*)ws;                                     // B*2DI*L
  float* xconv = (float*)(ws + (size_t)B_ * 2 * DI_ * L_ * 4);   // B*DI*L
  float* xdbl  = (float*)(ws + (size_t)B_ * 2 * DI_ * L_ * 4
                             + (size_t)B_ * DI_ * L_ * 4);       // B*96*L

  // K3 partials live in xz's b=0 x-half (dead between K2 and K4).
  float* part = xz;
  // BCt (B*L*16*2 floats = 524288 B) reuses xdbl's rows-0..64 region,
  // which is dead after K4 consumes it.
  float* BCt = xdbl;

  // K1 (bf16 MFMA): xz[b][e][l] = sum_d hs[b][l][d] * w1[e][d]
  {
    dim3 g(L_ / 128, (2 * DI_) / 128, B_);
    gemm_mfma<0, 0><<<g, 256, 0, stream>>>(w1, hs, xz,
        2 * DI_, L_, DM_, DM_, DM_, L_,
        0LL, (long long)L_ * DM_, (long long)2 * DI_ * L_);
  }

  // K2: depthwise conv + SiLU
  conv_silu_kernel<<<dim3(B_ * DI_ * L_ / 4 / 256), 256, 0, stream>>>(xz, cw, cb, xconv);

  // K3a (split-K partials, no atomics): part[kc][b][r][l]
  {
    dim3 g(L_ / 64, 2 * KC_, B_);
    gemm64_p<<<g, 256, 0, stream>>>(xpw, xconv, part,
        96, L_, DI_, DI_, L_,
        (long long)DI_ * L_);
  }
  // K3b: x_dbl = sum_kc part[kc]
  k3_reduce<<<dim3(B_ * 96 * L_ / 4 / 256), 256, 0, stream>>>(part, xdbl);

  // K4: dv[b][d][l] = softplus(sum_r dtw[d][r]*x_dbl[b][r][l] + dtb[d])
  {
    dim3 g(L_ / 64, DI_ / 64, B_);
    gemm64<0, 1, 1><<<g, 256, 0, stream>>>(dtw, xdbl, xz, dtbp,
        DI_, L_, DTR_, DTR_, L_, L_,
        0LL, (long long)96 * L_, (long long)2 * DI_ * L_);
  }

  // K4b: transpose B/C rows into BCt (after K4 freed xdbl rows 0..64)
  bc_transpose<<<dim3(L_ / 64, B_), 256, 0, stream>>>(xdbl, BCt);

  // K5: selective scan v7 (barrier-free, LDS-free, coalesced BCt loads)
  scan_kernel<<<dim3(B_ * DI_ / 16), 256, 0, stream>>>(xz, xconv, BCt, Alog, Dw);

  // K5b: gating y = y_pre * silu(z)
  gate_silu_kernel<<<dim3(B_ * DI_ * L_ / 4 / 256), 256, 0, stream>>>(xz);

  // K6 (bf16 MFMA, M=o): out[b][l][o] = sum_d y[b][d][l] * wo[o][d]
  {
    dim3 g(L_ / 128, DM_ / 128, B_);
    gemm_mfma<1, 1><<<g, 256, 0, stream>>>(wo, xz, out,
        DM_, L_, DI_, DI_, L_, DM_,
        0LL, (long long)2 * DI_ * L_, (long long)L_ * DM_);
  }
}

// Round 15
// 362.203 us; speedup vs baseline: 1.2274x; 1.2274x over previous
//
#include <hip/hip_runtime.h>
#include <hip/hip_bf16.h>

#define B_    2
#define L_    2048
#define DM_   1024
#define DI_   2048
#define DS_   16
#define DTR_  64
#define KC_   8

typedef __bf16 v8bf __attribute__((ext_vector_type(8)));
typedef float  v4f  __attribute__((ext_vector_type(4)));
typedef unsigned short us8 __attribute__((ext_vector_type(8)));

// HW packed fp32->bf16 (RNE): lo -> bits[15:0], hi -> bits[31:16].
__device__ __forceinline__ unsigned cvt_pk_bf16(float lo, float hi) {
  unsigned r;
  asm("v_cvt_pk_bf16_f32 %0, %1, %2" : "=v"(r) : "v"(lo), "v"(hi));
  return r;
}

// DPP row_shr reduction step; after shifts 1,2,4,8 the row sum lands in lane 15.
template<int CTRL>
__device__ __forceinline__ float dpp_shr_add(float x) {
  int xi = __builtin_bit_cast(int, x);
  int yi = __builtin_amdgcn_update_dpp(xi, xi, CTRL, 0xF, 0xF, true);
  return x + __builtin_bit_cast(float, yi);
}

// ---------------------------------------------------------------------------
// Pre-cast fp32 -> bf16 for K1 operands: w1 (4096x1024) then hs (2x2048x1024).
// 8 elems per thread.
// ---------------------------------------------------------------------------
#define W1_ELEMS (4096 * 1024)
#define HS_ELEMS (B_ * L_ * DM_)
__global__ __launch_bounds__(256) void cast2_bf16(
    const float* __restrict__ w1, const float* __restrict__ hs,
    unsigned short* __restrict__ w1b, unsigned short* __restrict__ hsb)
{
  size_t i8 = ((size_t)blockIdx.x * 256 + threadIdx.x) * 8;
  const float* src;
  unsigned short* dst;
  if (i8 < W1_ELEMS) { src = w1 + i8; dst = w1b + i8; }
  else               { src = hs + (i8 - W1_ELEMS); dst = hsb + (i8 - W1_ELEMS); }
  float4 a = *(const float4*)src;
  float4 b = *(const float4*)(src + 4);
  unsigned t32[4];
  t32[0] = cvt_pk_bf16(a.x, a.y);
  t32[1] = cvt_pk_bf16(a.z, a.w);
  t32[2] = cvt_pk_bf16(b.x, b.y);
  t32[3] = cvt_pk_bf16(b.z, b.w);
  *(uint4*)dst = *(const uint4*)t32;
}

// ---------------------------------------------------------------------------
// bf16 MFMA GEMM with PRE-CAST bf16 operands (K1). 128x128 tile, BK=32,
// 4 waves (2x2), 16x16x32 MFMA. Staging: 2x us8 loads per operand per thread,
// XOR-swizzled LDS writes (layout identical to validated gemm_mfma).
// C[m][n] = sum_k A[m*lda+k] * B[n*ldb+k], C row-major.
// ---------------------------------------------------------------------------
__global__ __launch_bounds__(256) void gemm_mfma_bb(
    const unsigned short* __restrict__ A, const unsigned short* __restrict__ B,
    float* __restrict__ C,
    int M, int N, int K, int lda, int ldb, int ldc,
    long long sA, long long sB_, long long sC)
{
  __shared__ unsigned short lA[128 * 32];
  __shared__ unsigned short lB[128 * 32];

  const int tid  = threadIdx.x;
  const int bz   = blockIdx.z;
  A += sA  * bz;
  B += sB_ * bz;
  C += sC  * bz;

  const int m0 = blockIdx.y * 128;
  const int n0 = blockIdx.x * 128;
  const int wave = tid >> 6, lane = tid & 63;
  const int wr = wave >> 1, wc = wave & 1;
  const int lrow = lane & 15, lk = lane >> 4;

  v4f acc[4][4];
  #pragma unroll
  for (int i = 0; i < 4; ++i)
    #pragma unroll
    for (int j = 0; j < 4; ++j) acc[i][j] = (v4f)0.f;

  const int sr  = tid >> 1, skh = (tid & 1) * 16;

  for (int k0 = 0; k0 < K; k0 += 32) {
    __syncthreads();
    {
      const unsigned short* src = A + (size_t)(m0 + sr) * lda + k0 + skh;
      us8 a0 = *(const us8*)src;
      us8 a1 = *(const us8*)(src + 8);
      int b0 = sr * 64 + skh * 2;
      int sw = (sr & 7) << 4;
      *(us8*)((char*)lA + ((b0)      ^ sw)) = a0;
      *(us8*)((char*)lA + ((b0 + 16) ^ sw)) = a1;
    }
    {
      const unsigned short* src = B + (size_t)(n0 + sr) * ldb + k0 + skh;
      us8 b0v = *(const us8*)src;
      us8 b1v = *(const us8*)(src + 8);
      int b0 = sr * 64 + skh * 2;
      int sw = (sr & 7) << 4;
      *(us8*)((char*)lB + ((b0)      ^ sw)) = b0v;
      *(us8*)((char*)lB + ((b0 + 16) ^ sw)) = b1v;
    }
    __syncthreads();

    v8bf af[4], bf[4];
    #pragma unroll
    for (int i = 0; i < 4; ++i) {
      int r  = wr * 64 + i * 16 + lrow;
      int b0 = (r * 64 + lk * 16) ^ ((r & 7) << 4);
      af[i] = __builtin_bit_cast(v8bf, *(const us8*)((const char*)lA + b0));
    }
    #pragma unroll
    for (int j = 0; j < 4; ++j) {
      int r  = wc * 64 + j * 16 + lrow;
      int b0 = (r * 64 + lk * 16) ^ ((r & 7) << 4);
      bf[j] = __builtin_bit_cast(v8bf, *(const us8*)((const char*)lB + b0));
    }
    #pragma unroll
    for (int i = 0; i < 4; ++i)
      #pragma unroll
      for (int j = 0; j < 4; ++j)
        acc[i][j] = __builtin_amdgcn_mfma_f32_16x16x32_bf16(af[i], bf[j], acc[i][j], 0, 0, 0);
  }

  #pragma unroll
  for (int i = 0; i < 4; ++i) {
    #pragma unroll
    for (int j = 0; j < 4; ++j) {
      int gm = m0 + wr * 64 + i * 16 + lk * 4;
      int gn = n0 + wc * 64 + j * 16 + lrow;
      #pragma unroll
      for (int r = 0; r < 4; ++r)
        C[(long long)(gm + r) * ldc + gn] = acc[i][j][r];
    }
  }
}

// ---------------------------------------------------------------------------
// bf16 MFMA GEMM, fp32 inputs with cvt_pk staging (round-12 exact; K6 only).
// ---------------------------------------------------------------------------
template<int BCOL, int CT>
__global__ __launch_bounds__(256) void gemm_mfma(
    const float* __restrict__ A, const float* __restrict__ B,
    float* __restrict__ C,
    int M, int N, int K, int lda, int ldb, int ldc,
    long long sA, long long sB_, long long sC)
{
  __shared__ unsigned short lA[128 * 32];
  __shared__ unsigned short lB[128 * 32];

  const int tid  = threadIdx.x;
  const int bz   = blockIdx.z;
  A += sA  * bz;
  B += sB_ * bz;
  C += sC  * bz;

  const int m0 = blockIdx.y * 128;
  const int n0 = blockIdx.x * 128;
  const int wave = tid >> 6, lane = tid & 63;
  const int wr = wave >> 1, wc = wave & 1;
  const int lrow = lane & 15, lk = lane >> 4;

  v4f acc[4][4];
  #pragma unroll
  for (int i = 0; i < 4; ++i)
    #pragma unroll
    for (int j = 0; j < 4; ++j) acc[i][j] = (v4f)0.f;

  const int sr  = tid >> 1, skh = (tid & 1) * 16;
  const int cn4 = (tid & 31) * 4, ck4 = (tid >> 5) * 4;

  for (int k0 = 0; k0 < K; k0 += 32) {
    __syncthreads();
    {
      const float* src = A + (long long)(m0 + sr) * lda + k0 + skh;
      unsigned t32[8];
      #pragma unroll
      for (int q = 0; q < 4; ++q) {
        float4 v = *(const float4*)(src + q * 4);
        t32[2*q]   = cvt_pk_bf16(v.x, v.y);
        t32[2*q+1] = cvt_pk_bf16(v.z, v.w);
      }
      int b0 = sr * 64 + skh * 2;
      int sw = (sr & 7) << 4;
      *(uint4*)((char*)lA + ((b0)      ^ sw)) = *(uint4*)&t32[0];
      *(uint4*)((char*)lA + ((b0 + 16) ^ sw)) = *(uint4*)&t32[4];
    }
    if (BCOL == 0) {
      const float* src = B + (long long)(n0 + sr) * ldb + k0 + skh;
      unsigned t32[8];
      #pragma unroll
      for (int q = 0; q < 4; ++q) {
        float4 v = *(const float4*)(src + q * 4);
        t32[2*q]   = cvt_pk_bf16(v.x, v.y);
        t32[2*q+1] = cvt_pk_bf16(v.z, v.w);
      }
      int b0 = sr * 64 + skh * 2;
      int sw = (sr & 7) << 4;
      *(uint4*)((char*)lB + ((b0)      ^ sw)) = *(uint4*)&t32[0];
      *(uint4*)((char*)lB + ((b0 + 16) ^ sw)) = *(uint4*)&t32[4];
    } else {
      float va[4][4];
      #pragma unroll
      for (int kk = 0; kk < 4; ++kk) {
        float4 v = *(const float4*)(B + (long long)(k0 + ck4 + kk) * ldb + n0 + cn4);
        va[kk][0] = v.x; va[kk][1] = v.y; va[kk][2] = v.z; va[kk][3] = v.w;
      }
      #pragma unroll
      for (int nn = 0; nn < 4; ++nn) {
        unsigned w01 = cvt_pk_bf16(va[0][nn], va[1][nn]);
        unsigned w23 = cvt_pk_bf16(va[2][nn], va[3][nn]);
        int row = cn4 + nn;
        int b0  = row * 64 + ck4 * 2;
        unsigned* dst = (unsigned*)((char*)lB + (b0 ^ ((row & 7) << 4)));
        dst[0] = w01;
        dst[1] = w23;
      }
    }
    __syncthreads();

    v8bf af[4], bf[4];
    #pragma unroll
    for (int i = 0; i < 4; ++i) {
      int r  = wr * 64 + i * 16 + lrow;
      int b0 = (r * 64 + lk * 16) ^ ((r & 7) << 4);
      af[i] = __builtin_bit_cast(v8bf, *(const us8*)((const char*)lA + b0));
    }
    #pragma unroll
    for (int j = 0; j < 4; ++j) {
      int r  = wc * 64 + j * 16 + lrow;
      int b0 = (r * 64 + lk * 16) ^ ((r & 7) << 4);
      bf[j] = __builtin_bit_cast(v8bf, *(const us8*)((const char*)lB + b0));
    }
    #pragma unroll
    for (int i = 0; i < 4; ++i)
      #pragma unroll
      for (int j = 0; j < 4; ++j)
        acc[i][j] = __builtin_amdgcn_mfma_f32_16x16x32_bf16(af[i], bf[j], acc[i][j], 0, 0, 0);
  }

  #pragma unroll
  for (int i = 0; i < 4; ++i) {
    #pragma unroll
    for (int j = 0; j < 4; ++j) {
      int gm = m0 + wr * 64 + i * 16 + lk * 4;
      int gn = n0 + wc * 64 + j * 16 + lrow;
      if (CT == 0) {
        #pragma unroll
        for (int r = 0; r < 4; ++r)
          C[(long long)(gm + r) * ldc + gn] = acc[i][j][r];
      } else {
        *(v4f*)&C[(long long)gn * ldc + gm] = acc[i][j];
      }
    }
  }
}

// ---------------------------------------------------------------------------
// Generic 64x64x16 fp32 tiled GEMM. ACT 1: softplus(acc + bias[m]) epilogue.
// ---------------------------------------------------------------------------
template<int AMODE, int BMODE, int ACT>
__global__ __launch_bounds__(256) void gemm64(
    const float* __restrict__ A, const float* __restrict__ B,
    float* __restrict__ C, const float* __restrict__ bias,
    int M, int N, int K, int lda, int ldb, int ldc,
    long long sA, long long sB_, long long sC)
{
  constexpr int BM = 64, BN = 64, BK = 16;
  __shared__ float As[BK][BM + 4];
  __shared__ float Bs[BK][BN + 4];

  const int tid = threadIdx.x;
  const int bz  = blockIdx.z;
  A += sA  * bz;
  B += sB_ * bz;
  C += sC  * bz;

  const int m0 = blockIdx.y * BM;
  const int n0 = blockIdx.x * BN;
  const int tx = tid & 15;
  const int ty = tid >> 4;

  float acc[4][4] = {};

  for (int k0 = 0; k0 < K; k0 += BK) {
    #pragma unroll
    for (int i = 0; i < 4; ++i) {
      int idx = tid + i * 256;
      int m, k;
      if (AMODE == 0) { k = idx & (BK - 1); m = idx >> 4; }
      else            { m = idx & (BM - 1); k = idx >> 6; }
      int gm = m0 + m;
      float v = 0.f;
      if (gm < M)
        v = (AMODE == 0) ? A[(long long)gm * lda + (k0 + k)]
                         : A[(long long)(k0 + k) * lda + gm];
      As[k][m] = v;
    }
    #pragma unroll
    for (int i = 0; i < 4; ++i) {
      int idx = tid + i * 256;
      int n, k;
      if (BMODE == 0) { k = idx & (BK - 1); n = idx >> 4; }
      else            { n = idx & (BN - 1); k = idx >> 6; }
      int gn = n0 + n;
      float v = (BMODE == 0) ? B[(long long)gn * ldb + (k0 + k)]
                             : B[(long long)(k0 + k) * ldb + gn];
      Bs[k][n] = v;
    }
    __syncthreads();

    #pragma unroll
    for (int k = 0; k < BK; ++k) {
      float4 av = *(const float4*)&As[k][ty * 4];
      float4 bv = *(const float4*)&Bs[k][tx * 4];
      float a_[4] = {av.x, av.y, av.z, av.w};
      float b_[4] = {bv.x, bv.y, bv.z, bv.w};
      #pragma unroll
      for (int i = 0; i < 4; ++i)
        #pragma unroll
        for (int j = 0; j < 4; ++j)
          acc[i][j] = fmaf(a_[i], b_[j], acc[i][j]);
    }
    __syncthreads();
  }

  #pragma unroll
  for (int i = 0; i < 4; ++i) {
    int gm = m0 + ty * 4 + i;
    if (gm < M) {
      float bv = (ACT == 1) ? bias[gm] : 0.f;
      #pragma unroll
      for (int j = 0; j < 4; ++j) {
        float v = acc[i][j];
        if (ACT == 1) {
          v += bv;
          v = (v > 20.f) ? v : __logf(1.f + __expf(v));
        }
        C[(long long)gm * ldc + n0 + tx * 4 + j] = v;
      }
    }
  }
}

// ---------------------------------------------------------------------------
// Split-K partials GEMM for K3 (round-9 exact). No atomics.
// ---------------------------------------------------------------------------
__global__ __launch_bounds__(256) void gemm64_p(
    const float* __restrict__ A, const float* __restrict__ B,
    float* __restrict__ part,
    int M, int N, int K, int lda, int ldb,
    long long sB_)
{
  constexpr int BM = 64, BN = 64, BK = 16;
  __shared__ float As[BK][BM + 4];
  __shared__ float Bs[BK][BN + 4];

  const int tid = threadIdx.x;
  const int bz  = blockIdx.z;
  B += sB_ * bz;

  const int m0  = (blockIdx.y & 1) * BM;
  const int kc  = blockIdx.y >> 1;
  const int n0  = blockIdx.x * BN;
  const int kend = (kc + 1) * (K / KC_);
  const int tx = tid & 15;
  const int ty = tid >> 4;

  float* Cp = part + ((size_t)(kc * B_ + bz) * 96) * (size_t)L_;

  float acc[4][4] = {};

  for (int k0 = kc * (K / KC_); k0 < kend; k0 += BK) {
    #pragma unroll
    for (int i = 0; i < 4; ++i) {
      int idx = tid + i * 256;
      int k = idx & (BK - 1), m = idx >> 4;
      int gm = m0 + m;
      As[k][m] = (gm < M) ? A[(long long)gm * lda + (k0 + k)] : 0.f;
    }
    #pragma unroll
    for (int i = 0; i < 4; ++i) {
      int idx = tid + i * 256;
      int n = idx & (BN - 1), k = idx >> 6;
      Bs[k][n] = B[(long long)(k0 + k) * ldb + (n0 + n)];
    }
    __syncthreads();

    #pragma unroll
    for (int k = 0; k < BK; ++k) {
      float4 av = *(const float4*)&As[k][ty * 4];
      float4 bv = *(const float4*)&Bs[k][tx * 4];
      float a_[4] = {av.x, av.y, av.z, av.w};
      float b_[4] = {bv.x, bv.y, bv.z, bv.w};
      #pragma unroll
      for (int i = 0; i < 4; ++i)
        #pragma unroll
        for (int j = 0; j < 4; ++j)
          acc[i][j] = fmaf(a_[i], b_[j], acc[i][j]);
    }
    __syncthreads();
  }

  #pragma unroll
  for (int i = 0; i < 4; ++i) {
    int gm = m0 + ty * 4 + i;
    if (gm < M)
      *(float4*)&Cp[(size_t)gm * L_ + n0 + tx * 4] = *(float4*)&acc[i][0];
  }
}

// reduce KC_ partial slabs -> x_dbl. One float4 per thread.
__global__ __launch_bounds__(256) void k3_reduce(
    const float* __restrict__ part, float* __restrict__ xdbl)
{
  int i   = blockIdx.x * 256 + threadIdx.x;     // [0, B*96*L/4)
  int l4  = (i & (L_ / 4 - 1)) << 2;
  int row = i >> 9;                              // b*96 + r
  float4 a = make_float4(0.f, 0.f, 0.f, 0.f);
  #pragma unroll
  for (int kc = 0; kc < KC_; ++kc) {
    float4 v = *(const float4*)&part[((size_t)(kc * B_ * 96 + row)) * L_ + l4];
    a.x += v.x; a.y += v.y; a.z += v.z; a.w += v.w;
  }
  *(float4*)&xdbl[(size_t)row * L_ + l4] = a;
}

// ---------------------------------------------------------------------------
// Depthwise causal conv (k=4) + bias + SiLU (round-1 exact).
// ---------------------------------------------------------------------------
__global__ __launch_bounds__(256) void conv_silu_kernel(
    const float* __restrict__ xz, const float* __restrict__ cw,
    const float* __restrict__ cb, float* __restrict__ xc)
{
  int idx = blockIdx.x * 256 + threadIdx.x;
  int l4  = (idx & (L_ / 4 - 1)) << 2;
  int row = idx >> 9;
  int d   = row & (DI_ - 1);
  int b   = row >> 11;

  const float* in = xz + ((size_t)b * 2 * DI_ + d) * L_;
  float w0 = cw[d * 4 + 0], w1 = cw[d * 4 + 1];
  float w2 = cw[d * 4 + 2], w3 = cw[d * 4 + 3];
  float bias = cb[d];

  float o[4];
  #pragma unroll
  for (int j = 0; j < 4; ++j) {
    int l = l4 + j;
    float acc = bias + in[l] * w3;
    if (l >= 1) acc += in[l - 1] * w2;
    if (l >= 2) acc += in[l - 2] * w1;
    if (l >= 3) acc += in[l - 3] * w0;
    float sig = 1.f / (1.f + __expf(-acc));
    o[j] = acc * sig;
  }
  *(float4*)&xc[(size_t)row * L_ + l4] = *(float4*)o;
}

// ---------------------------------------------------------------------------
// Gate kernel: y = y_pre * z * sigmoid(z) in place (round-13 exact).
// ---------------------------------------------------------------------------
__global__ __launch_bounds__(256) void gate_silu_kernel(float* __restrict__ xz)
{
  int idx = blockIdx.x * 256 + threadIdx.x;       // [0, B*DI*L/4)
  int l4  = (idx & (L_ / 4 - 1)) << 2;
  int row = idx >> 9;                              // b*DI + d
  int d   = row & (DI_ - 1);
  int b   = row >> 11;

  float*       y = xz + ((size_t)b * 2 * DI_ + d) * L_;
  const float* z = xz + ((size_t)b * 2 * DI_ + DI_ + d) * L_;

  float4 yv = *(const float4*)&y[l4];
  float4 zv = *(const float4*)&z[l4];
  float o[4] = {yv.x, yv.y, yv.z, yv.w};
  float zz[4] = {zv.x, zv.y, zv.z, zv.w};
  #pragma unroll
  for (int j = 0; j < 4; ++j) {
    float sig = 1.f / (1.f + __expf(-zz[j]));
    o[j] = o[j] * zz[j] * sig;
  }
  *(float4*)&y[l4] = *(const float4*)o;
}

// ---------------------------------------------------------------------------
// Selective scan v6 (round-13 exact): B/C LDS dbuf + direct uniform dv/x,
// DPP reduce -> lane 15 emits y_pre = p + x*D. dv pre-softplus'd by K4.
// ---------------------------------------------------------------------------
__global__ __launch_bounds__(256) void scan_kernel(
    float* __restrict__ xz, const float* __restrict__ xconv,
    const float* __restrict__ x_dbl, const float* __restrict__ A_log,
    const float* __restrict__ Dw)
{
  const int tid = threadIdx.x;
  const int g   = tid >> 4;
  const int n   = tid & 15;
  const int gid = blockIdx.x * 16 + g;
  const int b   = gid >> 11;
  const int d   = gid & (DI_ - 1);
  const int bb  = blockIdx.x >> 7;

  const float An = -expf(A_log[d * DS_ + n]);
  const float Dd = Dw[d];

  const float* drow = xz    + ((size_t)b * 2 * DI_ + d) * L_;
  const float* xrow = xconv + ((size_t)b * DI_ + d) * L_;
  float*       yrow = xz    + ((size_t)b * 2 * DI_ + d) * L_;

  const float* Bbase = x_dbl + ((size_t)bb * 96 + DTR_) * L_;
  const float* Cbase = x_dbl + ((size_t)bb * 96 + DTR_ + DS_) * L_;

  __shared__ float sB[2][16][68], sC[2][16][68];

  const int sr = tid >> 4, sc4 = (tid & 15) * 4;
  const size_t soff = (size_t)sr * L_ + sc4;

  float4 rB = *(const float4*)&Bbase[soff];
  float4 rC = *(const float4*)&Cbase[soff];

  float4 nD0 = *(const float4*)&drow[0], nD1 = *(const float4*)&drow[4];
  float4 nX0 = *(const float4*)&xrow[0], nX1 = *(const float4*)&xrow[4];

  float h = 0.f;
  int cur = 0;
  for (int l0 = 0; l0 < L_; l0 += 64) {
    *(float4*)&sB[cur][sr][sc4] = rB;
    *(float4*)&sC[cur][sr][sc4] = rC;
    if (l0 + 64 < L_) {
      rB = *(const float4*)&Bbase[soff + l0 + 64];
      rC = *(const float4*)&Cbase[soff + l0 + 64];
    }
    __syncthreads();

    #pragma unroll
    for (int l8 = 0; l8 < 64; l8 += 8) {
      const int l = l0 + l8;
      float dv[8], xv[8], Bn[8], Cn[8];
      *(float4*)&dv[0] = nD0; *(float4*)&dv[4] = nD1;
      *(float4*)&xv[0] = nX0; *(float4*)&xv[4] = nX1;

      if (l + 8 < L_) {
        nD0 = *(const float4*)&drow[l + 8]; nD1 = *(const float4*)&drow[l + 12];
        nX0 = *(const float4*)&xrow[l + 8]; nX1 = *(const float4*)&xrow[l + 12];
      }

      *(float4*)&Bn[0] = *(const float4*)&sB[cur][n][l8];
      *(float4*)&Bn[4] = *(const float4*)&sB[cur][n][l8 + 4];
      *(float4*)&Cn[0] = *(const float4*)&sC[cur][n][l8];
      *(float4*)&Cn[4] = *(const float4*)&sC[cur][n][l8 + 4];

      float dA[8], dBu[8];
      #pragma unroll
      for (int j = 0; j < 8; ++j) {
        dA[j]  = __expf(dv[j] * An);
        dBu[j] = dv[j] * Bn[j] * xv[j];
      }
      float p[8];
      #pragma unroll
      for (int j = 0; j < 8; ++j) {
        h = fmaf(dA[j], h, dBu[j]);
        p[j] = h * Cn[j];
      }
      #pragma unroll
      for (int j = 0; j < 8; ++j) p[j] = dpp_shr_add<0x111>(p[j]);
      #pragma unroll
      for (int j = 0; j < 8; ++j) p[j] = dpp_shr_add<0x112>(p[j]);
      #pragma unroll
      for (int j = 0; j < 8; ++j) p[j] = dpp_shr_add<0x114>(p[j]);
      #pragma unroll
      for (int j = 0; j < 8; ++j) p[j] = dpp_shr_add<0x118>(p[j]);

      if (n == 15) {
        float o[8];
        #pragma unroll
        for (int j = 0; j < 8; ++j)
          o[j] = p[j] + xv[j] * Dd;          // y_pre; gating applied later
        *(float4*)&yrow[l]     = *(const float4*)&o[0];
        *(float4*)&yrow[l + 4] = *(const float4*)&o[4];
      }
    }
    cur ^= 1;
  }
}

// ---------------------------------------------------------------------------
extern "C" void kernel_launch(void* const* d_in, const int* in_sizes, int n_in,
                              void* d_out, int out_size, void* d_ws, size_t ws_size,
                              hipStream_t stream)
{
  const float* hs   = (const float*)d_in[0];
  const float* w1   = (const float*)d_in[1];
  const float* cw   = (const float*)d_in[2];
  const float* cb   = (const float*)d_in[3];
  const float* xpw  = (const float*)d_in[4];
  const float* dtw  = (const float*)d_in[5];
  const float* dtbp = (const float*)d_in[6];
  const float* Alog = (const float*)d_in[7];
  const float* Dw   = (const float*)d_in[8];
  const float* wo   = (const float*)d_in[9];
  float* out = (float*)d_out;

  char* ws = (char*)d_ws;
  float* xz    = (float*)ws;                                     // B*2DI*L
  float* xconv = (float*)(ws + (size_t)B_ * 2 * DI_ * L_ * 4);   // B*DI*L
  float* xdbl  = (float*)(ws + (size_t)B_ * 2 * DI_ * L_ * 4
                             + (size_t)B_ * DI_ * L_ * 4);       // B*96*L

  // K3 partials live in xz's b=0 x-half (dead between K2 and K4).
  float* part = xz;
  // bf16 copies of w1/hs live in xconv region (dead until K2, after K1).
  unsigned short* w1b = (unsigned short*)xconv;
  unsigned short* hsb = w1b + (size_t)W1_ELEMS;

  // K0: pre-cast w1 + hs to bf16
  cast2_bf16<<<dim3((W1_ELEMS + HS_ELEMS) / 8 / 256), 256, 0, stream>>>(
      w1, hs, w1b, hsb);

  // K1 (bf16 MFMA, pre-cast operands): xz[b][e][l] = sum_d hs[b][l][d]*w1[e][d]
  {
    dim3 g(L_ / 128, (2 * DI_) / 128, B_);
    gemm_mfma_bb<<<g, 256, 0, stream>>>(w1b, hsb, xz,
        2 * DI_, L_, DM_, DM_, DM_, L_,
        0LL, (long long)L_ * DM_, (long long)2 * DI_ * L_);
  }

  // K2: depthwise conv + SiLU
  conv_silu_kernel<<<dim3(B_ * DI_ * L_ / 4 / 256), 256, 0, stream>>>(xz, cw, cb, xconv);

  // K3a (split-K partials, no atomics): part[kc][b][r][l]
  {
    dim3 g(L_ / 64, 2 * KC_, B_);
    gemm64_p<<<g, 256, 0, stream>>>(xpw, xconv, part,
        96, L_, DI_, DI_, L_,
        (long long)DI_ * L_);
  }
  // K3b: x_dbl = sum_kc part[kc]
  k3_reduce<<<dim3(B_ * 96 * L_ / 4 / 256), 256, 0, stream>>>(part, xdbl);

  // K4: dv[b][d][l] = softplus(sum_r dtw[d][r]*x_dbl[b][r][l] + dtb[d])
  {
    dim3 g(L_ / 64, DI_ / 64, B_);
    gemm64<0, 1, 1><<<g, 256, 0, stream>>>(dtw, xdbl, xz, dtbp,
        DI_, L_, DTR_, DTR_, L_, L_,
        0LL, (long long)96 * L_, (long long)2 * DI_ * L_);
  }

  // K5: selective scan v6 (round-13 exact)
  scan_kernel<<<dim3(B_ * DI_ / 16), 256, 0, stream>>>(xz, xconv, xdbl, Alog, Dw);

  // K5b: gating y = y_pre * silu(z)
  gate_silu_kernel<<<dim3(B_ * DI_ * L_ / 4 / 256), 256, 0, stream>>>(xz);

  // K6 (bf16 MFMA, M=o): out[b][l][o] = sum_d y[b][d][l] * wo[o][d]
  {
    dim3 g(L_ / 128, DM_ / 128, B_);
    gemm_mfma<1, 1><<<g, 256, 0, stream>>>(wo, xz, out,
        DM_, L_, DI_, DI_, L_, DM_,
        0LL, (long long)2 * DI_ * L_, (long long)L_ * DM_);
  }
}

// Round 16
// 354.240 us; speedup vs baseline: 1.2549x; 1.0225x over previous
//
#include <hip/hip_runtime.h>
#include <hip/hip_bf16.h>

#define B_    2
#define L_    2048
#define DM_   1024
#define DI_   2048
#define DS_   16
#define DTR_  64
#define KC_   8

typedef __bf16 v8bf __attribute__((ext_vector_type(8)));
typedef float  v4f  __attribute__((ext_vector_type(4)));
typedef unsigned short us8 __attribute__((ext_vector_type(8)));
typedef unsigned short us4 __attribute__((ext_vector_type(4)));

// HW packed fp32->bf16 (RNE): lo -> bits[15:0], hi -> bits[31:16].
__device__ __forceinline__ unsigned cvt_pk_bf16(float lo, float hi) {
  unsigned r;
  asm("v_cvt_pk_bf16_f32 %0, %1, %2" : "=v"(r) : "v"(lo), "v"(hi));
  return r;
}

// DPP row_shr reduction step; after shifts 1,2,4,8 the row sum lands in lane 15.
template<int CTRL>
__device__ __forceinline__ float dpp_shr_add(float x) {
  int xi = __builtin_bit_cast(int, x);
  int yi = __builtin_amdgcn_update_dpp(xi, xi, CTRL, 0xF, 0xF, true);
  return x + __builtin_bit_cast(float, yi);
}

// ---------------------------------------------------------------------------
// Pre-cast fp32 -> bf16 for K1 operands: w1 (4096x1024) then hs (2x2048x1024).
// ---------------------------------------------------------------------------
#define W1_ELEMS (4096 * 1024)
#define HS_ELEMS (B_ * L_ * DM_)
__global__ __launch_bounds__(256) void cast2_bf16(
    const float* __restrict__ w1, const float* __restrict__ hs,
    unsigned short* __restrict__ w1b, unsigned short* __restrict__ hsb)
{
  size_t i8 = ((size_t)blockIdx.x * 256 + threadIdx.x) * 8;
  const float* src;
  unsigned short* dst;
  if (i8 < W1_ELEMS) { src = w1 + i8; dst = w1b + i8; }
  else               { src = hs + (i8 - W1_ELEMS); dst = hsb + (i8 - W1_ELEMS); }
  float4 a = *(const float4*)src;
  float4 b = *(const float4*)(src + 4);
  unsigned t32[4];
  t32[0] = cvt_pk_bf16(a.x, a.y);
  t32[1] = cvt_pk_bf16(a.z, a.w);
  t32[2] = cvt_pk_bf16(b.x, b.y);
  t32[3] = cvt_pk_bf16(b.z, b.w);
  *(uint4*)dst = *(const uint4*)t32;
}

// Pre-cast wo (DM x DI) -> bf16. Runs after scan (region freed).
__global__ __launch_bounds__(256) void cast_wo_bf16(
    const float* __restrict__ wo, unsigned short* __restrict__ wob)
{
  size_t i8 = ((size_t)blockIdx.x * 256 + threadIdx.x) * 8;
  float4 a = *(const float4*)(wo + i8);
  float4 b = *(const float4*)(wo + i8 + 4);
  unsigned t32[4];
  t32[0] = cvt_pk_bf16(a.x, a.y);
  t32[1] = cvt_pk_bf16(a.z, a.w);
  t32[2] = cvt_pk_bf16(b.x, b.y);
  t32[3] = cvt_pk_bf16(b.z, b.w);
  *(uint4*)(wob + i8) = *(const uint4*)t32;
}

// ---------------------------------------------------------------------------
// bf16 MFMA GEMM with PRE-CAST bf16 operands, both K-contig (K1).
// (round-15 exact, validated)
// ---------------------------------------------------------------------------
__global__ __launch_bounds__(256) void gemm_mfma_bb(
    const unsigned short* __restrict__ A, const unsigned short* __restrict__ B,
    float* __restrict__ C,
    int M, int N, int K, int lda, int ldb, int ldc,
    long long sA, long long sB_, long long sC)
{
  __shared__ unsigned short lA[128 * 32];
  __shared__ unsigned short lB[128 * 32];

  const int tid  = threadIdx.x;
  const int bz   = blockIdx.z;
  A += sA  * bz;
  B += sB_ * bz;
  C += sC  * bz;

  const int m0 = blockIdx.y * 128;
  const int n0 = blockIdx.x * 128;
  const int wave = tid >> 6, lane = tid & 63;
  const int wr = wave >> 1, wc = wave & 1;
  const int lrow = lane & 15, lk = lane >> 4;

  v4f acc[4][4];
  #pragma unroll
  for (int i = 0; i < 4; ++i)
    #pragma unroll
    for (int j = 0; j < 4; ++j) acc[i][j] = (v4f)0.f;

  const int sr  = tid >> 1, skh = (tid & 1) * 16;

  for (int k0 = 0; k0 < K; k0 += 32) {
    __syncthreads();
    {
      const unsigned short* src = A + (size_t)(m0 + sr) * lda + k0 + skh;
      us8 a0 = *(const us8*)src;
      us8 a1 = *(const us8*)(src + 8);
      int b0 = sr * 64 + skh * 2;
      int sw = (sr & 7) << 4;
      *(us8*)((char*)lA + ((b0)      ^ sw)) = a0;
      *(us8*)((char*)lA + ((b0 + 16) ^ sw)) = a1;
    }
    {
      const unsigned short* src = B + (size_t)(n0 + sr) * ldb + k0 + skh;
      us8 b0v = *(const us8*)src;
      us8 b1v = *(const us8*)(src + 8);
      int b0 = sr * 64 + skh * 2;
      int sw = (sr & 7) << 4;
      *(us8*)((char*)lB + ((b0)      ^ sw)) = b0v;
      *(us8*)((char*)lB + ((b0 + 16) ^ sw)) = b1v;
    }
    __syncthreads();

    v8bf af[4], bf[4];
    #pragma unroll
    for (int i = 0; i < 4; ++i) {
      int r  = wr * 64 + i * 16 + lrow;
      int b0 = (r * 64 + lk * 16) ^ ((r & 7) << 4);
      af[i] = __builtin_bit_cast(v8bf, *(const us8*)((const char*)lA + b0));
    }
    #pragma unroll
    for (int j = 0; j < 4; ++j) {
      int r  = wc * 64 + j * 16 + lrow;
      int b0 = (r * 64 + lk * 16) ^ ((r & 7) << 4);
      bf[j] = __builtin_bit_cast(v8bf, *(const us8*)((const char*)lB + b0));
    }
    #pragma unroll
    for (int i = 0; i < 4; ++i)
      #pragma unroll
      for (int j = 0; j < 4; ++j)
        acc[i][j] = __builtin_amdgcn_mfma_f32_16x16x32_bf16(af[i], bf[j], acc[i][j], 0, 0, 0);
  }

  #pragma unroll
  for (int i = 0; i < 4; ++i) {
    #pragma unroll
    for (int j = 0; j < 4; ++j) {
      int gm = m0 + wr * 64 + i * 16 + lk * 4;
      int gn = n0 + wc * 64 + j * 16 + lrow;
      #pragma unroll
      for (int r = 0; r < 4; ++r)
        C[(long long)(gm + r) * ldc + gn] = acc[i][j][r];
    }
  }
}

// ---------------------------------------------------------------------------
// bf16 MFMA GEMM, PRE-CAST operands, B N-contig col-staged, C transposed (K6).
// A: [M][K] bf16 K-contig. B: b(n,k) = B[k*ldb + n] bf16. C[n*ldc + m].
// Staging-load paths bf16-pure; fragment/MFMA/epilogue identical to validated.
// ---------------------------------------------------------------------------
__global__ __launch_bounds__(256) void gemm_mfma_bb2(
    const unsigned short* __restrict__ A, const unsigned short* __restrict__ B,
    float* __restrict__ C,
    int M, int N, int K, int lda, int ldb, int ldc,
    long long sA, long long sB_, long long sC)
{
  __shared__ unsigned short lA[128 * 32];
  __shared__ unsigned short lB[128 * 32];

  const int tid  = threadIdx.x;
  const int bz   = blockIdx.z;
  A += sA  * bz;
  B += sB_ * bz;
  C += sC  * bz;

  const int m0 = blockIdx.y * 128;
  const int n0 = blockIdx.x * 128;
  const int wave = tid >> 6, lane = tid & 63;
  const int wr = wave >> 1, wc = wave & 1;
  const int lrow = lane & 15, lk = lane >> 4;

  v4f acc[4][4];
  #pragma unroll
  for (int i = 0; i < 4; ++i)
    #pragma unroll
    for (int j = 0; j < 4; ++j) acc[i][j] = (v4f)0.f;

  const int sr  = tid >> 1, skh = (tid & 1) * 16;
  const int cn4 = (tid & 31) * 4, ck4 = (tid >> 5) * 4;

  for (int k0 = 0; k0 < K; k0 += 32) {
    __syncthreads();
    // A: row-staged, 2x us8
    {
      const unsigned short* src = A + (size_t)(m0 + sr) * lda + k0 + skh;
      us8 a0 = *(const us8*)src;
      us8 a1 = *(const us8*)(src + 8);
      int b0 = sr * 64 + skh * 2;
      int sw = (sr & 7) << 4;
      *(us8*)((char*)lA + ((b0)      ^ sw)) = a0;
      *(us8*)((char*)lA + ((b0 + 16) ^ sw)) = a1;
    }
    // B: col-staged, ushort4 loads + in-register transpose (no cvt)
    {
      us4 va[4];
      #pragma unroll
      for (int kk = 0; kk < 4; ++kk)
        va[kk] = *(const us4*)(B + (size_t)(k0 + ck4 + kk) * ldb + n0 + cn4);
      #pragma unroll
      for (int nn = 0; nn < 4; ++nn) {
        us4 w;
        w[0] = va[0][nn]; w[1] = va[1][nn];
        w[2] = va[2][nn]; w[3] = va[3][nn];
        int row = cn4 + nn;
        int b0  = row * 64 + ck4 * 2;
        *(us4*)((char*)lB + (b0 ^ ((row & 7) << 4))) = w;
      }
    }
    __syncthreads();

    v8bf af[4], bf[4];
    #pragma unroll
    for (int i = 0; i < 4; ++i) {
      int r  = wr * 64 + i * 16 + lrow;
      int b0 = (r * 64 + lk * 16) ^ ((r & 7) << 4);
      af[i] = __builtin_bit_cast(v8bf, *(const us8*)((const char*)lA + b0));
    }
    #pragma unroll
    for (int j = 0; j < 4; ++j) {
      int r  = wc * 64 + j * 16 + lrow;
      int b0 = (r * 64 + lk * 16) ^ ((r & 7) << 4);
      bf[j] = __builtin_bit_cast(v8bf, *(const us8*)((const char*)lB + b0));
    }
    #pragma unroll
    for (int i = 0; i < 4; ++i)
      #pragma unroll
      for (int j = 0; j < 4; ++j)
        acc[i][j] = __builtin_amdgcn_mfma_f32_16x16x32_bf16(af[i], bf[j], acc[i][j], 0, 0, 0);
  }

  #pragma unroll
  for (int i = 0; i < 4; ++i) {
    #pragma unroll
    for (int j = 0; j < 4; ++j) {
      int gm = m0 + wr * 64 + i * 16 + lk * 4;
      int gn = n0 + wc * 64 + j * 16 + lrow;
      *(v4f*)&C[(long long)gn * ldc + gm] = acc[i][j];
    }
  }
}

// ---------------------------------------------------------------------------
// Generic 64x64x16 fp32 tiled GEMM. ACT 1: softplus(acc + bias[m]) epilogue.
// ---------------------------------------------------------------------------
template<int AMODE, int BMODE, int ACT>
__global__ __launch_bounds__(256) void gemm64(
    const float* __restrict__ A, const float* __restrict__ B,
    float* __restrict__ C, const float* __restrict__ bias,
    int M, int N, int K, int lda, int ldb, int ldc,
    long long sA, long long sB_, long long sC)
{
  constexpr int BM = 64, BN = 64, BK = 16;
  __shared__ float As[BK][BM + 4];
  __shared__ float Bs[BK][BN + 4];

  const int tid = threadIdx.x;
  const int bz  = blockIdx.z;
  A += sA  * bz;
  B += sB_ * bz;
  C += sC  * bz;

  const int m0 = blockIdx.y * BM;
  const int n0 = blockIdx.x * BN;
  const int tx = tid & 15;
  const int ty = tid >> 4;

  float acc[4][4] = {};

  for (int k0 = 0; k0 < K; k0 += BK) {
    #pragma unroll
    for (int i = 0; i < 4; ++i) {
      int idx = tid + i * 256;
      int m, k;
      if (AMODE == 0) { k = idx & (BK - 1); m = idx >> 4; }
      else            { m = idx & (BM - 1); k = idx >> 6; }
      int gm = m0 + m;
      float v = 0.f;
      if (gm < M)
        v = (AMODE == 0) ? A[(long long)gm * lda + (k0 + k)]
                         : A[(long long)(k0 + k) * lda + gm];
      As[k][m] = v;
    }
    #pragma unroll
    for (int i = 0; i < 4; ++i) {
      int idx = tid + i * 256;
      int n, k;
      if (BMODE == 0) { k = idx & (BK - 1); n = idx >> 4; }
      else            { n = idx & (BN - 1); k = idx >> 6; }
      int gn = n0 + n;
      float v = (BMODE == 0) ? B[(long long)gn * ldb + (k0 + k)]
                             : B[(long long)(k0 + k) * ldb + gn];
      Bs[k][n] = v;
    }
    __syncthreads();

    #pragma unroll
    for (int k = 0; k < BK; ++k) {
      float4 av = *(const float4*)&As[k][ty * 4];
      float4 bv = *(const float4*)&Bs[k][tx * 4];
      float a_[4] = {av.x, av.y, av.z, av.w};
      float b_[4] = {bv.x, bv.y, bv.z, bv.w};
      #pragma unroll
      for (int i = 0; i < 4; ++i)
        #pragma unroll
        for (int j = 0; j < 4; ++j)
          acc[i][j] = fmaf(a_[i], b_[j], acc[i][j]);
    }
    __syncthreads();
  }

  #pragma unroll
  for (int i = 0; i < 4; ++i) {
    int gm = m0 + ty * 4 + i;
    if (gm < M) {
      float bv = (ACT == 1) ? bias[gm] : 0.f;
      #pragma unroll
      for (int j = 0; j < 4; ++j) {
        float v = acc[i][j];
        if (ACT == 1) {
          v += bv;
          v = (v > 20.f) ? v : __logf(1.f + __expf(v));
        }
        C[(long long)gm * ldc + n0 + tx * 4 + j] = v;
      }
    }
  }
}

// ---------------------------------------------------------------------------
// Split-K partials GEMM for K3 (round-9 exact). No atomics.
// ---------------------------------------------------------------------------
__global__ __launch_bounds__(256) void gemm64_p(
    const float* __restrict__ A, const float* __restrict__ B,
    float* __restrict__ part,
    int M, int N, int K, int lda, int ldb,
    long long sB_)
{
  constexpr int BM = 64, BN = 64, BK = 16;
  __shared__ float As[BK][BM + 4];
  __shared__ float Bs[BK][BN + 4];

  const int tid = threadIdx.x;
  const int bz  = blockIdx.z;
  B += sB_ * bz;

  const int m0  = (blockIdx.y & 1) * BM;
  const int kc  = blockIdx.y >> 1;
  const int n0  = blockIdx.x * BN;
  const int kend = (kc + 1) * (K / KC_);
  const int tx = tid & 15;
  const int ty = tid >> 4;

  float* Cp = part + ((size_t)(kc * B_ + bz) * 96) * (size_t)L_;

  float acc[4][4] = {};

  for (int k0 = kc * (K / KC_); k0 < kend; k0 += BK) {
    #pragma unroll
    for (int i = 0; i < 4; ++i) {
      int idx = tid + i * 256;
      int k = idx & (BK - 1), m = idx >> 4;
      int gm = m0 + m;
      As[k][m] = (gm < M) ? A[(long long)gm * lda + (k0 + k)] : 0.f;
    }
    #pragma unroll
    for (int i = 0; i < 4; ++i) {
      int idx = tid + i * 256;
      int n = idx & (BN - 1), k = idx >> 6;
      Bs[k][n] = B[(long long)(k0 + k) * ldb + (n0 + n)];
    }
    __syncthreads();

    #pragma unroll
    for (int k = 0; k < BK; ++k) {
      float4 av = *(const float4*)&As[k][ty * 4];
      float4 bv = *(const float4*)&Bs[k][tx * 4];
      float a_[4] = {av.x, av.y, av.z, av.w};
      float b_[4] = {bv.x, bv.y, bv.z, bv.w};
      #pragma unroll
      for (int i = 0; i < 4; ++i)
        #pragma unroll
        for (int j = 0; j < 4; ++j)
          acc[i][j] = fmaf(a_[i], b_[j], acc[i][j]);
    }
    __syncthreads();
  }

  #pragma unroll
  for (int i = 0; i < 4; ++i) {
    int gm = m0 + ty * 4 + i;
    if (gm < M)
      *(float4*)&Cp[(size_t)gm * L_ + n0 + tx * 4] = *(float4*)&acc[i][0];
  }
}

// reduce KC_ partial slabs -> x_dbl. One float4 per thread.
__global__ __launch_bounds__(256) void k3_reduce(
    const float* __restrict__ part, float* __restrict__ xdbl)
{
  int i   = blockIdx.x * 256 + threadIdx.x;     // [0, B*96*L/4)
  int l4  = (i & (L_ / 4 - 1)) << 2;
  int row = i >> 9;                              // b*96 + r
  float4 a = make_float4(0.f, 0.f, 0.f, 0.f);
  #pragma unroll
  for (int kc = 0; kc < KC_; ++kc) {
    float4 v = *(const float4*)&part[((size_t)(kc * B_ * 96 + row)) * L_ + l4];
    a.x += v.x; a.y += v.y; a.z += v.z; a.w += v.w;
  }
  *(float4*)&xdbl[(size_t)row * L_ + l4] = a;
}

// ---------------------------------------------------------------------------
// Depthwise causal conv (k=4) + bias + SiLU (round-1 exact).
// ---------------------------------------------------------------------------
__global__ __launch_bounds__(256) void conv_silu_kernel(
    const float* __restrict__ xz, const float* __restrict__ cw,
    const float* __restrict__ cb, float* __restrict__ xc)
{
  int idx = blockIdx.x * 256 + threadIdx.x;
  int l4  = (idx & (L_ / 4 - 1)) << 2;
  int row = idx >> 9;
  int d   = row & (DI_ - 1);
  int b   = row >> 11;

  const float* in = xz + ((size_t)b * 2 * DI_ + d) * L_;
  float w0 = cw[d * 4 + 0], w1 = cw[d * 4 + 1];
  float w2 = cw[d * 4 + 2], w3 = cw[d * 4 + 3];
  float bias = cb[d];

  float o[4];
  #pragma unroll
  for (int j = 0; j < 4; ++j) {
    int l = l4 + j;
    float acc = bias + in[l] * w3;
    if (l >= 1) acc += in[l - 1] * w2;
    if (l >= 2) acc += in[l - 2] * w1;
    if (l >= 3) acc += in[l - 3] * w0;
    float sig = 1.f / (1.f + __expf(-acc));
    o[j] = acc * sig;
  }
  *(float4*)&xc[(size_t)row * L_ + l4] = *(float4*)o;
}

// ---------------------------------------------------------------------------
// Gate kernel: yb[b][d][l] = bf16( y_pre * z * sigmoid(z) ).
// Reads y_pre (xz x-half) + z (xz z-half); writes bf16 into ybf (xconv
// region, dead after scan). 8 elems per thread.
// ---------------------------------------------------------------------------
__global__ __launch_bounds__(256) void gate_silu_bf16_kernel(
    const float* __restrict__ xz, unsigned short* __restrict__ ybf)
{
  int idx = blockIdx.x * 256 + threadIdx.x;       // [0, B*DI*L/8)
  int l8  = (idx & (L_ / 8 - 1)) << 3;
  int row = idx >> 8;                              // b*DI + d
  int d   = row & (DI_ - 1);
  int b   = row >> 11;

  const float* y = xz + ((size_t)b * 2 * DI_ + d) * L_ + l8;
  const float* z = xz + ((size_t)b * 2 * DI_ + DI_ + d) * L_ + l8;

  float yv[8], zv[8];
  *(float4*)&yv[0] = *(const float4*)y;
  *(float4*)&yv[4] = *(const float4*)(y + 4);
  *(float4*)&zv[0] = *(const float4*)z;
  *(float4*)&zv[4] = *(const float4*)(z + 4);

  float o[8];
  #pragma unroll
  for (int j = 0; j < 8; ++j) {
    float sig = 1.f / (1.f + __expf(-zv[j]));
    o[j] = yv[j] * zv[j] * sig;
  }
  unsigned t32[4];
  t32[0] = cvt_pk_bf16(o[0], o[1]);
  t32[1] = cvt_pk_bf16(o[2], o[3]);
  t32[2] = cvt_pk_bf16(o[4], o[5]);
  t32[3] = cvt_pk_bf16(o[6], o[7]);
  *(uint4*)(ybf + (size_t)row * L_ + l8) = *(const uint4*)t32;
}

// ---------------------------------------------------------------------------
// Selective scan v6 (round-13 exact): B/C LDS dbuf + direct uniform dv/x,
// DPP reduce -> lane 15 emits y_pre = p + x*D. dv pre-softplus'd by K4.
// ---------------------------------------------------------------------------
__global__ __launch_bounds__(256) void scan_kernel(
    float* __restrict__ xz, const float* __restrict__ xconv,
    const float* __restrict__ x_dbl, const float* __restrict__ A_log,
    const float* __restrict__ Dw)
{
  const int tid = threadIdx.x;
  const int g   = tid >> 4;
  const int n   = tid & 15;
  const int gid = blockIdx.x * 16 + g;
  const int b   = gid >> 11;
  const int d   = gid & (DI_ - 1);
  const int bb  = blockIdx.x >> 7;

  const float An = -expf(A_log[d * DS_ + n]);
  const float Dd = Dw[d];

  const float* drow = xz    + ((size_t)b * 2 * DI_ + d) * L_;
  const float* xrow = xconv + ((size_t)b * DI_ + d) * L_;
  float*       yrow = xz    + ((size_t)b * 2 * DI_ + d) * L_;

  const float* Bbase = x_dbl + ((size_t)bb * 96 + DTR_) * L_;
  const float* Cbase = x_dbl + ((size_t)bb * 96 + DTR_ + DS_) * L_;

  __shared__ float sB[2][16][68], sC[2][16][68];

  const int sr = tid >> 4, sc4 = (tid & 15) * 4;
  const size_t soff = (size_t)sr * L_ + sc4;

  float4 rB = *(const float4*)&Bbase[soff];
  float4 rC = *(const float4*)&Cbase[soff];

  float4 nD0 = *(const float4*)&drow[0], nD1 = *(const float4*)&drow[4];
  float4 nX0 = *(const float4*)&xrow[0], nX1 = *(const float4*)&xrow[4];

  float h = 0.f;
  int cur = 0;
  for (int l0 = 0; l0 < L_; l0 += 64) {
    *(float4*)&sB[cur][sr][sc4] = rB;
    *(float4*)&sC[cur][sr][sc4] = rC;
    if (l0 + 64 < L_) {
      rB = *(const float4*)&Bbase[soff + l0 + 64];
      rC = *(const float4*)&Cbase[soff + l0 + 64];
    }
    __syncthreads();

    #pragma unroll
    for (int l8 = 0; l8 < 64; l8 += 8) {
      const int l = l0 + l8;
      float dv[8], xv[8], Bn[8], Cn[8];
      *(float4*)&dv[0] = nD0; *(float4*)&dv[4] = nD1;
      *(float4*)&xv[0] = nX0; *(float4*)&xv[4] = nX1;

      if (l + 8 < L_) {
        nD0 = *(const float4*)&drow[l + 8]; nD1 = *(const float4*)&drow[l + 12];
        nX0 = *(const float4*)&xrow[l + 8]; nX1 = *(const float4*)&xrow[l + 12];
      }

      *(float4*)&Bn[0] = *(const float4*)&sB[cur][n][l8];
      *(float4*)&Bn[4] = *(const float4*)&sB[cur][n][l8 + 4];
      *(float4*)&Cn[0] = *(const float4*)&sC[cur][n][l8];
      *(float4*)&Cn[4] = *(const float4*)&sC[cur][n][l8 + 4];

      float dA[8], dBu[8];
      #pragma unroll
      for (int j = 0; j < 8; ++j) {
        dA[j]  = __expf(dv[j] * An);
        dBu[j] = dv[j] * Bn[j] * xv[j];
      }
      float p[8];
      #pragma unroll
      for (int j = 0; j < 8; ++j) {
        h = fmaf(dA[j], h, dBu[j]);
        p[j] = h * Cn[j];
      }
      #pragma unroll
      for (int j = 0; j < 8; ++j) p[j] = dpp_shr_add<0x111>(p[j]);
      #pragma unroll
      for (int j = 0; j < 8; ++j) p[j] = dpp_shr_add<0x112>(p[j]);
      #pragma unroll
      for (int j = 0; j < 8; ++j) p[j] = dpp_shr_add<0x114>(p[j]);
      #pragma unroll
      for (int j = 0; j < 8; ++j) p[j] = dpp_shr_add<0x118>(p[j]);

      if (n == 15) {
        float o[8];
        #pragma unroll
        for (int j = 0; j < 8; ++j)
          o[j] = p[j] + xv[j] * Dd;          // y_pre; gating applied later
        *(float4*)&yrow[l]     = *(const float4*)&o[0];
        *(float4*)&yrow[l + 4] = *(const float4*)&o[4];
      }
    }
    cur ^= 1;
  }
}

// ---------------------------------------------------------------------------
extern "C" void kernel_launch(void* const* d_in, const int* in_sizes, int n_in,
                              void* d_out, int out_size, void* d_ws, size_t ws_size,
                              hipStream_t stream)
{
  const float* hs   = (const float*)d_in[0];
  const float* w1   = (const float*)d_in[1];
  const float* cw   = (const float*)d_in[2];
  const float* cb   = (const float*)d_in[3];
  const float* xpw  = (const float*)d_in[4];
  const float* dtw  = (const float*)d_in[5];
  const float* dtbp = (const float*)d_in[6];
  const float* Alog = (const float*)d_in[7];
  const float* Dw   = (const float*)d_in[8];
  const float* wo   = (const float*)d_in[9];
  float* out = (float*)d_out;

  char* ws = (char*)d_ws;
  float* xz    = (float*)ws;                                     // B*2DI*L
  float* xconv = (float*)(ws + (size_t)B_ * 2 * DI_ * L_ * 4);   // B*DI*L
  float* xdbl  = (float*)(ws + (size_t)B_ * 2 * DI_ * L_ * 4
                             + (size_t)B_ * DI_ * L_ * 4);       // B*96*L

  // K3 partials live in xz's b=0 x-half (dead between K2 and K4).
  float* part = xz;
  // bf16 copies of w1/hs live in xconv region (dead until K2, after K1).
  unsigned short* w1b = (unsigned short*)xconv;
  unsigned short* hsb = w1b + (size_t)W1_ELEMS;
  // After the scan (xconv's last reader), the region is recycled:
  //   ybf [0 .. B*DI*L ushorts) ; wob [B*DI*L .. +DM*DI ushorts)
  unsigned short* ybf = (unsigned short*)xconv;
  unsigned short* wob = ybf + (size_t)B_ * DI_ * L_;

  // K0: pre-cast w1 + hs to bf16
  cast2_bf16<<<dim3((W1_ELEMS + HS_ELEMS) / 8 / 256), 256, 0, stream>>>(
      w1, hs, w1b, hsb);

  // K1 (bf16 MFMA, pre-cast operands): xz[b][e][l] = sum_d hs[b][l][d]*w1[e][d]
  {
    dim3 g(L_ / 128, (2 * DI_) / 128, B_);
    gemm_mfma_bb<<<g, 256, 0, stream>>>(w1b, hsb, xz,
        2 * DI_, L_, DM_, DM_, DM_, L_,
        0LL, (long long)L_ * DM_, (long long)2 * DI_ * L_);
  }

  // K2: depthwise conv + SiLU
  conv_silu_kernel<<<dim3(B_ * DI_ * L_ / 4 / 256), 256, 0, stream>>>(xz, cw, cb, xconv);

  // K3a (split-K partials, no atomics): part[kc][b][r][l]
  {
    dim3 g(L_ / 64, 2 * KC_, B_);
    gemm64_p<<<g, 256, 0, stream>>>(xpw, xconv, part,
        96, L_, DI_, DI_, L_,
        (long long)DI_ * L_);
  }
  // K3b: x_dbl = sum_kc part[kc]
  k3_reduce<<<dim3(B_ * 96 * L_ / 4 / 256), 256, 0, stream>>>(part, xdbl);

  // K4: dv[b][d][l] = softplus(sum_r dtw[d][r]*x_dbl[b][r][l] + dtb[d])
  {
    dim3 g(L_ / 64, DI_ / 64, B_);
    gemm64<0, 1, 1><<<g, 256, 0, stream>>>(dtw, xdbl, xz, dtbp,
        DI_, L_, DTR_, DTR_, L_, L_,
        0LL, (long long)96 * L_, (long long)2 * DI_ * L_);
  }

  // K5: selective scan v6 (round-13 exact; last reader of xconv)
  scan_kernel<<<dim3(B_ * DI_ / 16), 256, 0, stream>>>(xz, xconv, xdbl, Alog, Dw);

  // K5b: gating -> bf16 y into recycled xconv region
  gate_silu_bf16_kernel<<<dim3(B_ * DI_ * L_ / 8 / 256), 256, 0, stream>>>(xz, ybf);

  // K5c: pre-cast wo to bf16 (disjoint part of recycled xconv region)
  cast_wo_bf16<<<dim3(DM_ * DI_ / 8 / 256), 256, 0, stream>>>(wo, wob);

  // K6 (bf16 MFMA, pre-cast operands, M=o): out[b][l][o] = sum_d y[b][d][l]*wo[o][d]
  {
    dim3 g(L_ / 128, DM_ / 128, B_);
    gemm_mfma_bb2<<<g, 256, 0, stream>>>(wob, ybf, out,
        DM_, L_, DI_, DI_, L_, DM_,
        0LL, (long long)DI_ * L_, (long long)L_ * DM_);
  }
}

// Round 17
// 347.325 us; speedup vs baseline: 1.2799x; 1.0199x over previous
//
#include <hip/hip_runtime.h>
#include <hip/hip_bf16.h>

#define B_    2
#define L_    2048
#define DM_   1024
#define DI_   2048
#define DS_   16
#define DTR_  64
#define KC_   8

typedef __bf16 v8bf __attribute__((ext_vector_type(8)));
typedef float  v4f  __attribute__((ext_vector_type(4)));
typedef unsigned short us8 __attribute__((ext_vector_type(8)));
typedef unsigned short us4 __attribute__((ext_vector_type(4)));

// HW packed fp32->bf16 (RNE): lo -> bits[15:0], hi -> bits[31:16].
__device__ __forceinline__ unsigned cvt_pk_bf16(float lo, float hi) {
  unsigned r;
  asm("v_cvt_pk_bf16_f32 %0, %1, %2" : "=v"(r) : "v"(lo), "v"(hi));
  return r;
}

// DPP row_shr reduction step; after shifts 1,2,4,8 the row sum lands in lane 15.
template<int CTRL>
__device__ __forceinline__ float dpp_shr_add(float x) {
  int xi = __builtin_bit_cast(int, x);
  int yi = __builtin_amdgcn_update_dpp(xi, xi, CTRL, 0xF, 0xF, true);
  return x + __builtin_bit_cast(float, yi);
}

// ---------------------------------------------------------------------------
// Pre-cast fp32 -> bf16 for K1 operands: w1 (4096x1024) then hs (2x2048x1024).
// ---------------------------------------------------------------------------
#define W1_ELEMS (4096 * 1024)
#define HS_ELEMS (B_ * L_ * DM_)
__global__ __launch_bounds__(256) void cast2_bf16(
    const float* __restrict__ w1, const float* __restrict__ hs,
    unsigned short* __restrict__ w1b, unsigned short* __restrict__ hsb)
{
  size_t i8 = ((size_t)blockIdx.x * 256 + threadIdx.x) * 8;
  const float* src;
  unsigned short* dst;
  if (i8 < W1_ELEMS) { src = w1 + i8; dst = w1b + i8; }
  else               { src = hs + (i8 - W1_ELEMS); dst = hsb + (i8 - W1_ELEMS); }
  float4 a = *(const float4*)src;
  float4 b = *(const float4*)(src + 4);
  unsigned t32[4];
  t32[0] = cvt_pk_bf16(a.x, a.y);
  t32[1] = cvt_pk_bf16(a.z, a.w);
  t32[2] = cvt_pk_bf16(b.x, b.y);
  t32[3] = cvt_pk_bf16(b.z, b.w);
  *(uint4*)dst = *(const uint4*)t32;
}

// Pre-cast wo (DM x DI) -> bf16. Runs after scan (region freed).
__global__ __launch_bounds__(256) void cast_wo_bf16(
    const float* __restrict__ wo, unsigned short* __restrict__ wob)
{
  size_t i8 = ((size_t)blockIdx.x * 256 + threadIdx.x) * 8;
  float4 a = *(const float4*)(wo + i8);
  float4 b = *(const float4*)(wo + i8 + 4);
  unsigned t32[4];
  t32[0] = cvt_pk_bf16(a.x, a.y);
  t32[1] = cvt_pk_bf16(a.z, a.w);
  t32[2] = cvt_pk_bf16(b.x, b.y);
  t32[3] = cvt_pk_bf16(b.z, b.w);
  *(uint4*)(wob + i8) = *(const uint4*)t32;
}

// ---------------------------------------------------------------------------
// bf16 MFMA GEMM with PRE-CAST bf16 operands, both K-contig (K1).
// (round-15 exact, validated)
// ---------------------------------------------------------------------------
__global__ __launch_bounds__(256) void gemm_mfma_bb(
    const unsigned short* __restrict__ A, const unsigned short* __restrict__ B,
    float* __restrict__ C,
    int M, int N, int K, int lda, int ldb, int ldc,
    long long sA, long long sB_, long long sC)
{
  __shared__ unsigned short lA[128 * 32];
  __shared__ unsigned short lB[128 * 32];

  const int tid  = threadIdx.x;
  const int bz   = blockIdx.z;
  A += sA  * bz;
  B += sB_ * bz;
  C += sC  * bz;

  const int m0 = blockIdx.y * 128;
  const int n0 = blockIdx.x * 128;
  const int wave = tid >> 6, lane = tid & 63;
  const int wr = wave >> 1, wc = wave & 1;
  const int lrow = lane & 15, lk = lane >> 4;

  v4f acc[4][4];
  #pragma unroll
  for (int i = 0; i < 4; ++i)
    #pragma unroll
    for (int j = 0; j < 4; ++j) acc[i][j] = (v4f)0.f;

  const int sr  = tid >> 1, skh = (tid & 1) * 16;

  for (int k0 = 0; k0 < K; k0 += 32) {
    __syncthreads();
    {
      const unsigned short* src = A + (size_t)(m0 + sr) * lda + k0 + skh;
      us8 a0 = *(const us8*)src;
      us8 a1 = *(const us8*)(src + 8);
      int b0 = sr * 64 + skh * 2;
      int sw = (sr & 7) << 4;
      *(us8*)((char*)lA + ((b0)      ^ sw)) = a0;
      *(us8*)((char*)lA + ((b0 + 16) ^ sw)) = a1;
    }
    {
      const unsigned short* src = B + (size_t)(n0 + sr) * ldb + k0 + skh;
      us8 b0v = *(const us8*)src;
      us8 b1v = *(const us8*)(src + 8);
      int b0 = sr * 64 + skh * 2;
      int sw = (sr & 7) << 4;
      *(us8*)((char*)lB + ((b0)      ^ sw)) = b0v;
      *(us8*)((char*)lB + ((b0 + 16) ^ sw)) = b1v;
    }
    __syncthreads();

    v8bf af[4], bf[4];
    #pragma unroll
    for (int i = 0; i < 4; ++i) {
      int r  = wr * 64 + i * 16 + lrow;
      int b0 = (r * 64 + lk * 16) ^ ((r & 7) << 4);
      af[i] = __builtin_bit_cast(v8bf, *(const us8*)((const char*)lA + b0));
    }
    #pragma unroll
    for (int j = 0; j < 4; ++j) {
      int r  = wc * 64 + j * 16 + lrow;
      int b0 = (r * 64 + lk * 16) ^ ((r & 7) << 4);
      bf[j] = __builtin_bit_cast(v8bf, *(const us8*)((const char*)lB + b0));
    }
    #pragma unroll
    for (int i = 0; i < 4; ++i)
      #pragma unroll
      for (int j = 0; j < 4; ++j)
        acc[i][j] = __builtin_amdgcn_mfma_f32_16x16x32_bf16(af[i], bf[j], acc[i][j], 0, 0, 0);
  }

  #pragma unroll
  for (int i = 0; i < 4; ++i) {
    #pragma unroll
    for (int j = 0; j < 4; ++j) {
      int gm = m0 + wr * 64 + i * 16 + lk * 4;
      int gn = n0 + wc * 64 + j * 16 + lrow;
      #pragma unroll
      for (int r = 0; r < 4; ++r)
        C[(long long)(gm + r) * ldc + gn] = acc[i][j][r];
    }
  }
}

// ---------------------------------------------------------------------------
// bf16 MFMA GEMM, PRE-CAST operands, B N-contig col-staged, C transposed (K6).
// (round-16 exact, validated)
// ---------------------------------------------------------------------------
__global__ __launch_bounds__(256) void gemm_mfma_bb2(
    const unsigned short* __restrict__ A, const unsigned short* __restrict__ B,
    float* __restrict__ C,
    int M, int N, int K, int lda, int ldb, int ldc,
    long long sA, long long sB_, long long sC)
{
  __shared__ unsigned short lA[128 * 32];
  __shared__ unsigned short lB[128 * 32];

  const int tid  = threadIdx.x;
  const int bz   = blockIdx.z;
  A += sA  * bz;
  B += sB_ * bz;
  C += sC  * bz;

  const int m0 = blockIdx.y * 128;
  const int n0 = blockIdx.x * 128;
  const int wave = tid >> 6, lane = tid & 63;
  const int wr = wave >> 1, wc = wave & 1;
  const int lrow = lane & 15, lk = lane >> 4;

  v4f acc[4][4];
  #pragma unroll
  for (int i = 0; i < 4; ++i)
    #pragma unroll
    for (int j = 0; j < 4; ++j) acc[i][j] = (v4f)0.f;

  const int sr  = tid >> 1, skh = (tid & 1) * 16;
  const int cn4 = (tid & 31) * 4, ck4 = (tid >> 5) * 4;

  for (int k0 = 0; k0 < K; k0 += 32) {
    __syncthreads();
    {
      const unsigned short* src = A + (size_t)(m0 + sr) * lda + k0 + skh;
      us8 a0 = *(const us8*)src;
      us8 a1 = *(const us8*)(src + 8);
      int b0 = sr * 64 + skh * 2;
      int sw = (sr & 7) << 4;
      *(us8*)((char*)lA + ((b0)      ^ sw)) = a0;
      *(us8*)((char*)lA + ((b0 + 16) ^ sw)) = a1;
    }
    {
      us4 va[4];
      #pragma unroll
      for (int kk = 0; kk < 4; ++kk)
        va[kk] = *(const us4*)(B + (size_t)(k0 + ck4 + kk) * ldb + n0 + cn4);
      #pragma unroll
      for (int nn = 0; nn < 4; ++nn) {
        us4 w;
        w[0] = va[0][nn]; w[1] = va[1][nn];
        w[2] = va[2][nn]; w[3] = va[3][nn];
        int row = cn4 + nn;
        int b0  = row * 64 + ck4 * 2;
        *(us4*)((char*)lB + (b0 ^ ((row & 7) << 4))) = w;
      }
    }
    __syncthreads();

    v8bf af[4], bf[4];
    #pragma unroll
    for (int i = 0; i < 4; ++i) {
      int r  = wr * 64 + i * 16 + lrow;
      int b0 = (r * 64 + lk * 16) ^ ((r & 7) << 4);
      af[i] = __builtin_bit_cast(v8bf, *(const us8*)((const char*)lA + b0));
    }
    #pragma unroll
    for (int j = 0; j < 4; ++j) {
      int r  = wc * 64 + j * 16 + lrow;
      int b0 = (r * 64 + lk * 16) ^ ((r & 7) << 4);
      bf[j] = __builtin_bit_cast(v8bf, *(const us8*)((const char*)lB + b0));
    }
    #pragma unroll
    for (int i = 0; i < 4; ++i)
      #pragma unroll
      for (int j = 0; j < 4; ++j)
        acc[i][j] = __builtin_amdgcn_mfma_f32_16x16x32_bf16(af[i], bf[j], acc[i][j], 0, 0, 0);
  }

  #pragma unroll
  for (int i = 0; i < 4; ++i) {
    #pragma unroll
    for (int j = 0; j < 4; ++j) {
      int gm = m0 + wr * 64 + i * 16 + lk * 4;
      int gn = n0 + wc * 64 + j * 16 + lrow;
      *(v4f*)&C[(long long)gn * ldc + gm] = acc[i][j];
    }
  }
}

// ---------------------------------------------------------------------------
// Generic 64x64x16 fp32 tiled GEMM. ACT 1: softplus(acc + bias[m]) epilogue.
// ---------------------------------------------------------------------------
template<int AMODE, int BMODE, int ACT>
__global__ __launch_bounds__(256) void gemm64(
    const float* __restrict__ A, const float* __restrict__ B,
    float* __restrict__ C, const float* __restrict__ bias,
    int M, int N, int K, int lda, int ldb, int ldc,
    long long sA, long long sB_, long long sC)
{
  constexpr int BM = 64, BN = 64, BK = 16;
  __shared__ float As[BK][BM + 4];
  __shared__ float Bs[BK][BN + 4];

  const int tid = threadIdx.x;
  const int bz  = blockIdx.z;
  A += sA  * bz;
  B += sB_ * bz;
  C += sC  * bz;

  const int m0 = blockIdx.y * BM;
  const int n0 = blockIdx.x * BN;
  const int tx = tid & 15;
  const int ty = tid >> 4;

  float acc[4][4] = {};

  for (int k0 = 0; k0 < K; k0 += BK) {
    #pragma unroll
    for (int i = 0; i < 4; ++i) {
      int idx = tid + i * 256;
      int m, k;
      if (AMODE == 0) { k = idx & (BK - 1); m = idx >> 4; }
      else            { m = idx & (BM - 1); k = idx >> 6; }
      int gm = m0 + m;
      float v = 0.f;
      if (gm < M)
        v = (AMODE == 0) ? A[(long long)gm * lda + (k0 + k)]
                         : A[(long long)(k0 + k) * lda + gm];
      As[k][m] = v;
    }
    #pragma unroll
    for (int i = 0; i < 4; ++i) {
      int idx = tid + i * 256;
      int n, k;
      if (BMODE == 0) { k = idx & (BK - 1); n = idx >> 4; }
      else            { n = idx & (BN - 1); k = idx >> 6; }
      int gn = n0 + n;
      float v = (BMODE == 0) ? B[(long long)gn * ldb + (k0 + k)]
                             : B[(long long)(k0 + k) * ldb + gn];
      Bs[k][n] = v;
    }
    __syncthreads();

    #pragma unroll
    for (int k = 0; k < BK; ++k) {
      float4 av = *(const float4*)&As[k][ty * 4];
      float4 bv = *(const float4*)&Bs[k][tx * 4];
      float a_[4] = {av.x, av.y, av.z, av.w};
      float b_[4] = {bv.x, bv.y, bv.z, bv.w};
      #pragma unroll
      for (int i = 0; i < 4; ++i)
        #pragma unroll
        for (int j = 0; j < 4; ++j)
          acc[i][j] = fmaf(a_[i], b_[j], acc[i][j]);
    }
    __syncthreads();
  }

  #pragma unroll
  for (int i = 0; i < 4; ++i) {
    int gm = m0 + ty * 4 + i;
    if (gm < M) {
      float bv = (ACT == 1) ? bias[gm] : 0.f;
      #pragma unroll
      for (int j = 0; j < 4; ++j) {
        float v = acc[i][j];
        if (ACT == 1) {
          v += bv;
          v = (v > 20.f) ? v : __logf(1.f + __expf(v));
        }
        C[(long long)gm * ldc + n0 + tx * 4 + j] = v;
      }
    }
  }
}

// ---------------------------------------------------------------------------
// Split-K partials GEMM for K3 (round-9 exact). No atomics.
// ---------------------------------------------------------------------------
__global__ __launch_bounds__(256) void gemm64_p(
    const float* __restrict__ A, const float* __restrict__ B,
    float* __restrict__ part,
    int M, int N, int K, int lda, int ldb,
    long long sB_)
{
  constexpr int BM = 64, BN = 64, BK = 16;
  __shared__ float As[BK][BM + 4];
  __shared__ float Bs[BK][BN + 4];

  const int tid = threadIdx.x;
  const int bz  = blockIdx.z;
  B += sB_ * bz;

  const int m0  = (blockIdx.y & 1) * BM;
  const int kc  = blockIdx.y >> 1;
  const int n0  = blockIdx.x * BN;
  const int kend = (kc + 1) * (K / KC_);
  const int tx = tid & 15;
  const int ty = tid >> 4;

  float* Cp = part + ((size_t)(kc * B_ + bz) * 96) * (size_t)L_;

  float acc[4][4] = {};

  for (int k0 = kc * (K / KC_); k0 < kend; k0 += BK) {
    #pragma unroll
    for (int i = 0; i < 4; ++i) {
      int idx = tid + i * 256;
      int k = idx & (BK - 1), m = idx >> 4;
      int gm = m0 + m;
      As[k][m] = (gm < M) ? A[(long long)gm * lda + (k0 + k)] : 0.f;
    }
    #pragma unroll
    for (int i = 0; i < 4; ++i) {
      int idx = tid + i * 256;
      int n = idx & (BN - 1), k = idx >> 6;
      Bs[k][n] = B[(long long)(k0 + k) * ldb + (n0 + n)];
    }
    __syncthreads();

    #pragma unroll
    for (int k = 0; k < BK; ++k) {
      float4 av = *(const float4*)&As[k][ty * 4];
      float4 bv = *(const float4*)&Bs[k][tx * 4];
      float a_[4] = {av.x, av.y, av.z, av.w};
      float b_[4] = {bv.x, bv.y, bv.z, bv.w};
      #pragma unroll
      for (int i = 0; i < 4; ++i)
        #pragma unroll
        for (int j = 0; j < 4; ++j)
          acc[i][j] = fmaf(a_[i], b_[j], acc[i][j]);
    }
    __syncthreads();
  }

  #pragma unroll
  for (int i = 0; i < 4; ++i) {
    int gm = m0 + ty * 4 + i;
    if (gm < M)
      *(float4*)&Cp[(size_t)gm * L_ + n0 + tx * 4] = *(float4*)&acc[i][0];
  }
}

// reduce KC_ partial slabs -> x_dbl. One float4 per thread.
__global__ __launch_bounds__(256) void k3_reduce(
    const float* __restrict__ part, float* __restrict__ xdbl)
{
  int i   = blockIdx.x * 256 + threadIdx.x;     // [0, B*96*L/4)
  int l4  = (i & (L_ / 4 - 1)) << 2;
  int row = i >> 9;                              // b*96 + r
  float4 a = make_float4(0.f, 0.f, 0.f, 0.f);
  #pragma unroll
  for (int kc = 0; kc < KC_; ++kc) {
    float4 v = *(const float4*)&part[((size_t)(kc * B_ * 96 + row)) * L_ + l4];
    a.x += v.x; a.y += v.y; a.z += v.z; a.w += v.w;
  }
  *(float4*)&xdbl[(size_t)row * L_ + l4] = a;
}

// ---------------------------------------------------------------------------
// Depthwise causal conv (k=4) + bias + SiLU (round-1 exact).
// ---------------------------------------------------------------------------
__global__ __launch_bounds__(256) void conv_silu_kernel(
    const float* __restrict__ xz, const float* __restrict__ cw,
    const float* __restrict__ cb, float* __restrict__ xc)
{
  int idx = blockIdx.x * 256 + threadIdx.x;
  int l4  = (idx & (L_ / 4 - 1)) << 2;
  int row = idx >> 9;
  int d   = row & (DI_ - 1);
  int b   = row >> 11;

  const float* in = xz + ((size_t)b * 2 * DI_ + d) * L_;
  float w0 = cw[d * 4 + 0], w1 = cw[d * 4 + 1];
  float w2 = cw[d * 4 + 2], w3 = cw[d * 4 + 3];
  float bias = cb[d];

  float o[4];
  #pragma unroll
  for (int j = 0; j < 4; ++j) {
    int l = l4 + j;
    float acc = bias + in[l] * w3;
    if (l >= 1) acc += in[l - 1] * w2;
    if (l >= 2) acc += in[l - 2] * w1;
    if (l >= 3) acc += in[l - 3] * w0;
    float sig = 1.f / (1.f + __expf(-acc));
    o[j] = acc * sig;
  }
  *(float4*)&xc[(size_t)row * L_ + l4] = *(float4*)o;
}

// ---------------------------------------------------------------------------
// Gate kernel: yb[b][d][l] = bf16( y_pre * z * sigmoid(z) ) (round-16 exact).
// ---------------------------------------------------------------------------
__global__ __launch_bounds__(256) void gate_silu_bf16_kernel(
    const float* __restrict__ xz, unsigned short* __restrict__ ybf)
{
  int idx = blockIdx.x * 256 + threadIdx.x;       // [0, B*DI*L/8)
  int l8  = (idx & (L_ / 8 - 1)) << 3;
  int row = idx >> 8;                              // b*DI + d
  int d   = row & (DI_ - 1);
  int b   = row >> 11;

  const float* y = xz + ((size_t)b * 2 * DI_ + d) * L_ + l8;
  const float* z = xz + ((size_t)b * 2 * DI_ + DI_ + d) * L_ + l8;

  float yv[8], zv[8];
  *(float4*)&yv[0] = *(const float4*)y;
  *(float4*)&yv[4] = *(const float4*)(y + 4);
  *(float4*)&zv[0] = *(const float4*)z;
  *(float4*)&zv[4] = *(const float4*)(z + 4);

  float o[8];
  #pragma unroll
  for (int j = 0; j < 8; ++j) {
    float sig = 1.f / (1.f + __expf(-zv[j]));
    o[j] = yv[j] * zv[j] * sig;
  }
  unsigned t32[4];
  t32[0] = cvt_pk_bf16(o[0], o[1]);
  t32[1] = cvt_pk_bf16(o[2], o[3]);
  t32[2] = cvt_pk_bf16(o[4], o[5]);
  t32[3] = cvt_pk_bf16(o[6], o[7]);
  *(uint4*)(ybf + (size_t)row * L_ + l8) = *(const uint4*)t32;
}

// ---------------------------------------------------------------------------
// Selective scan v8: round-13 structure + one-batch-ahead LDS->register
// prefetch of B/C (primes batch 0 after the chunk barrier; batch i prefetches
// batch i+1 during compute; last batch pre-loaded). Same barrier semantics.
// Emits y_pre = p + x*D; dv pre-softplus'd by K4; gating applied later.
// ---------------------------------------------------------------------------
__global__ __launch_bounds__(256) void scan_kernel(
    float* __restrict__ xz, const float* __restrict__ xconv,
    const float* __restrict__ x_dbl, const float* __restrict__ A_log,
    const float* __restrict__ Dw)
{
  const int tid = threadIdx.x;
  const int g   = tid >> 4;
  const int n   = tid & 15;
  const int gid = blockIdx.x * 16 + g;
  const int b   = gid >> 11;
  const int d   = gid & (DI_ - 1);
  const int bb  = blockIdx.x >> 7;

  const float An = -expf(A_log[d * DS_ + n]);
  const float Dd = Dw[d];

  const float* drow = xz    + ((size_t)b * 2 * DI_ + d) * L_;
  const float* xrow = xconv + ((size_t)b * DI_ + d) * L_;
  float*       yrow = xz    + ((size_t)b * 2 * DI_ + d) * L_;

  const float* Bbase = x_dbl + ((size_t)bb * 96 + DTR_) * L_;
  const float* Cbase = x_dbl + ((size_t)bb * 96 + DTR_ + DS_) * L_;

  __shared__ float sB[2][16][68], sC[2][16][68];

  const int sr = tid >> 4, sc4 = (tid & 15) * 4;
  const size_t soff = (size_t)sr * L_ + sc4;

  float4 rB = *(const float4*)&Bbase[soff];
  float4 rC = *(const float4*)&Cbase[soff];

  float4 nD0 = *(const float4*)&drow[0], nD1 = *(const float4*)&drow[4];
  float4 nX0 = *(const float4*)&xrow[0], nX1 = *(const float4*)&xrow[4];

  float h = 0.f;
  int cur = 0;
  for (int l0 = 0; l0 < L_; l0 += 64) {
    *(float4*)&sB[cur][sr][sc4] = rB;
    *(float4*)&sC[cur][sr][sc4] = rC;
    if (l0 + 64 < L_) {
      rB = *(const float4*)&Bbase[soff + l0 + 64];
      rC = *(const float4*)&Cbase[soff + l0 + 64];
    }
    __syncthreads();

    // prime batch-0 B/C from LDS
    float4 mB0 = *(const float4*)&sB[cur][n][0];
    float4 mB1 = *(const float4*)&sB[cur][n][4];
    float4 mC0 = *(const float4*)&sC[cur][n][0];
    float4 mC1 = *(const float4*)&sC[cur][n][4];

    #pragma unroll
    for (int l8 = 0; l8 < 64; l8 += 8) {
      const int l = l0 + l8;
      float dv[8], xv[8], Bn[8], Cn[8];
      *(float4*)&dv[0] = nD0; *(float4*)&dv[4] = nD1;
      *(float4*)&xv[0] = nX0; *(float4*)&xv[4] = nX1;
      *(float4*)&Bn[0] = mB0; *(float4*)&Bn[4] = mB1;
      *(float4*)&Cn[0] = mC0; *(float4*)&Cn[4] = mC1;

      // global prefetch: next batch dv/x
      if (l + 8 < L_) {
        nD0 = *(const float4*)&drow[l + 8]; nD1 = *(const float4*)&drow[l + 12];
        nX0 = *(const float4*)&xrow[l + 8]; nX1 = *(const float4*)&xrow[l + 12];
      }
      // LDS prefetch: next batch B/C (within this chunk's buffer)
      if (l8 + 8 < 64) {
        mB0 = *(const float4*)&sB[cur][n][l8 + 8];
        mB1 = *(const float4*)&sB[cur][n][l8 + 12];
        mC0 = *(const float4*)&sC[cur][n][l8 + 8];
        mC1 = *(const float4*)&sC[cur][n][l8 + 12];
      }

      float dA[8], dBu[8];
      #pragma unroll
      for (int j = 0; j < 8; ++j) {
        dA[j]  = __expf(dv[j] * An);
        dBu[j] = dv[j] * Bn[j] * xv[j];
      }
      float p[8];
      #pragma unroll
      for (int j = 0; j < 8; ++j) {
        h = fmaf(dA[j], h, dBu[j]);
        p[j] = h * Cn[j];
      }
      #pragma unroll
      for (int j = 0; j < 8; ++j) p[j] = dpp_shr_add<0x111>(p[j]);
      #pragma unroll
      for (int j = 0; j < 8; ++j) p[j] = dpp_shr_add<0x112>(p[j]);
      #pragma unroll
      for (int j = 0; j < 8; ++j) p[j] = dpp_shr_add<0x114>(p[j]);
      #pragma unroll
      for (int j = 0; j < 8; ++j) p[j] = dpp_shr_add<0x118>(p[j]);

      if (n == 15) {
        float o[8];
        #pragma unroll
        for (int j = 0; j < 8; ++j)
          o[j] = p[j] + xv[j] * Dd;          // y_pre; gating applied later
        *(float4*)&yrow[l]     = *(const float4*)&o[0];
        *(float4*)&yrow[l + 4] = *(const float4*)&o[4];
      }
    }
    cur ^= 1;
  }
}

// ---------------------------------------------------------------------------
extern "C" void kernel_launch(void* const* d_in, const int* in_sizes, int n_in,
                              void* d_out, int out_size, void* d_ws, size_t ws_size,
                              hipStream_t stream)
{
  const float* hs   = (const float*)d_in[0];
  const float* w1   = (const float*)d_in[1];
  const float* cw   = (const float*)d_in[2];
  const float* cb   = (const float*)d_in[3];
  const float* xpw  = (const float*)d_in[4];
  const float* dtw  = (const float*)d_in[5];
  const float* dtbp = (const float*)d_in[6];
  const float* Alog = (const float*)d_in[7];
  const float* Dw   = (const float*)d_in[8];
  const float* wo   = (const float*)d_in[9];
  float* out = (float*)d_out;

  char* ws = (char*)d_ws;
  float* xz    = (float*)ws;                                     // B*2DI*L
  float* xconv = (float*)(ws + (size_t)B_ * 2 * DI_ * L_ * 4);   // B*DI*L
  float* xdbl  = (float*)(ws + (size_t)B_ * 2 * DI_ * L_ * 4
                             + (size_t)B_ * DI_ * L_ * 4);       // B*96*L

  // K3 partials live in xz's b=0 x-half (dead between K2 and K4).
  float* part = xz;
  // bf16 copies of w1/hs live in xconv region (dead until K2, after K1).
  unsigned short* w1b = (unsigned short*)xconv;
  unsigned short* hsb = w1b + (size_t)W1_ELEMS;
  // After the scan (xconv's last reader), the region is recycled:
  //   ybf [0 .. B*DI*L ushorts) ; wob [B*DI*L .. +DM*DI ushorts)
  unsigned short* ybf = (unsigned short*)xconv;
  unsigned short* wob = ybf + (size_t)B_ * DI_ * L_;

  // K0: pre-cast w1 + hs to bf16
  cast2_bf16<<<dim3((W1_ELEMS + HS_ELEMS) / 8 / 256), 256, 0, stream>>>(
      w1, hs, w1b, hsb);

  // K1 (bf16 MFMA, pre-cast operands): xz[b][e][l] = sum_d hs[b][l][d]*w1[e][d]
  {
    dim3 g(L_ / 128, (2 * DI_) / 128, B_);
    gemm_mfma_bb<<<g, 256, 0, stream>>>(w1b, hsb, xz,
        2 * DI_, L_, DM_, DM_, DM_, L_,
        0LL, (long long)L_ * DM_, (long long)2 * DI_ * L_);
  }

  // K2: depthwise conv + SiLU
  conv_silu_kernel<<<dim3(B_ * DI_ * L_ / 4 / 256), 256, 0, stream>>>(xz, cw, cb, xconv);

  // K3a (split-K partials, no atomics): part[kc][b][r][l]
  {
    dim3 g(L_ / 64, 2 * KC_, B_);
    gemm64_p<<<g, 256, 0, stream>>>(xpw, xconv, part,
        96, L_, DI_, DI_, L_,
        (long long)DI_ * L_);
  }
  // K3b: x_dbl = sum_kc part[kc]
  k3_reduce<<<dim3(B_ * 96 * L_ / 4 / 256), 256, 0, stream>>>(part, xdbl);

  // K4: dv[b][d][l] = softplus(sum_r dtw[d][r]*x_dbl[b][r][l] + dtb[d])
  {
    dim3 g(L_ / 64, DI_ / 64, B_);
    gemm64<0, 1, 1><<<g, 256, 0, stream>>>(dtw, xdbl, xz, dtbp,
        DI_, L_, DTR_, DTR_, L_, L_,
        0LL, (long long)96 * L_, (long long)2 * DI_ * L_);
  }

  // K5: selective scan v8 (LDS-read prefetch)
  scan_kernel<<<dim3(B_ * DI_ / 16), 256, 0, stream>>>(xz, xconv, xdbl, Alog, Dw);

  // K5b: gating -> bf16 y into recycled xconv region
  gate_silu_bf16_kernel<<<dim3(B_ * DI_ * L_ / 8 / 256), 256, 0, stream>>>(xz, ybf);

  // K5c: pre-cast wo to bf16 (disjoint part of recycled xconv region)
  cast_wo_bf16<<<dim3(DM_ * DI_ / 8 / 256), 256, 0, stream>>>(wo, wob);

  // K6 (bf16 MFMA, pre-cast operands, M=o): out[b][l][o] = sum_d y[b][d][l]*wo[o][d]
  {
    dim3 g(L_ / 128, DM_ / 128, B_);
    gemm_mfma_bb2<<<g, 256, 0, stream>>>(wob, ybf, out,
        DM_, L_, DI_, DI_, L_, DM_,
        0LL, (long long)DI_ * L_, (long long)L_ * DM_);
  }
}